// Round 1
// baseline (2224.159 us; speedup 1.0000x reference)
//
#include <hip/hip_runtime.h>
#include <hip/hip_bf16.h>

// ---------------------------------------------------------------------------
// ExpandAndContractBottleneck: up-conv stack -> sparse softmax-topK bottleneck
// -> down-conv stack.  All f32 (top-K selection needs f32 accuracy: the
// down-stack BatchNorms amplify the sparse contributions ~1e7x, and the
// rank-512 order-statistic gap (~1e-4) exceeds bf16 error (~1e-3)).
// ---------------------------------------------------------------------------

#define DEV_INLINE __device__ __forceinline__

constexpr int NB   = 8;      // batch
constexpr int NC   = 128;    // channels
constexpr int NH   = 1024;   // hidden channels
constexpr int LFULL= 8192;   // sparse frames
constexpr int KSEL = 512;    // k_sparse
constexpr int CAP  = 32768;  // candidate capacity per batch

DEV_INLINE unsigned monoKey(float f) {
    unsigned u = __float_as_uint(f);
    return (u & 0x80000000u) ? ~u : (u | 0x80000000u);
}
DEV_INLINE float keyToF(unsigned k) {
    unsigned u = (k & 0x80000000u) ? (k ^ 0x80000000u) : ~k;
    return __uint_as_float(u);
}
DEV_INLINE float lrelu(float v) { return v >= 0.f ? v : 0.2f * v; }

// ---------------------------------------------------------------------------
// Generic conv kernel.
//  - block: 256 threads -> tile of 128 out-channels x 64 output positions
//  - per-thread: 8 oc x 4 consecutive t  (32 accumulators)
//  - UPS: input is conceptually repeat(x,2) (nearest upsample), handled in
//    staging (xs holds the post-repeat, post-transform window incl. zero pad)
//  - INMODE: 0 = raw input, 1 = scale/shift (BN apply), 2 = scale/shift+lrelu
//  - OUTACT: lrelu on output (down stack: conv -> lrelu -> BN-stats)
//  - STATS:  accumulate per-channel sum / sumsq of the stored value
// ---------------------------------------------------------------------------
template<int KW, int STRIDE, int PAD, bool UPS, int INMODE, bool OUTACT, bool STATS>
__global__ __launch_bounds__(256) void conv_k(
    const float* __restrict__ in, float* __restrict__ out,
    const float* __restrict__ w, const float* __restrict__ bias,
    const float* __restrict__ scsh, float* __restrict__ stats,
    int L_in, int L_out)
{
    constexpr int CC    = (KW == 7) ? 8 : 16;
    constexpr int SPAN0 = 64 * STRIDE + KW - 1;
    constexpr int SPAN  = (SPAN0 + 3) & ~3;       // float4-aligned row
    constexpr int WROW  = 132;                    // padded (bank-spread, 16B rows)
    constexpr int NQ    = (3 * STRIDE + KW + 3) / 4;

    __shared__ float xs[CC][SPAN];
    __shared__ float wl[CC * KW][WROW];

    const int b   = blockIdx.y;
    const int t0  = blockIdx.x * 64;
    const int tid = threadIdx.x;
    const int og  = tid >> 4;       // 16 groups of 8 out-channels
    const int tl  = tid & 15;       // 16 lanes of 4 consecutive t
    const int Lc  = UPS ? 2 * L_in : L_in;
    const int p_base = t0 * STRIDE - PAD;

    float acc[8][4];
#pragma unroll
    for (int i = 0; i < 8; i++)
#pragma unroll
        for (int j = 0; j < 4; j++) acc[i][j] = 0.f;

    for (int cc = 0; cc < NC; cc += CC) {
        // ---- stage input window (transform + pad applied here) ----
        for (int idx = tid; idx < CC * SPAN0; idx += 256) {
            int cl = idx / SPAN0, pp = idx - cl * SPAN0;
            int c = cc + cl;
            int p = p_base + pp;
            float v = 0.f;
            if (p >= 0 && p < Lc) {
                int g = UPS ? (p >> 1) : p;
                float r = in[(b * NC + c) * L_in + g];
                if (INMODE > 0) {
                    float t_ = r * scsh[c] + scsh[NC + c];
                    v = (INMODE == 2) ? lrelu(t_) : t_;
                } else v = r;
            }
            xs[cl][pp] = v;
        }
        // ---- stage weights as wl[c_local*KW+k][oc] ----
        for (int idx = tid; idx < NC * CC * KW; idx += 256) {
            int o = idx / (CC * KW), r = idx - o * (CC * KW);
            wl[r][o] = w[o * (NC * KW) + cc * KW + r];
        }
        __syncthreads();

#pragma unroll 2
        for (int ci = 0; ci < CC; ci++) {
            float qf[NQ * 4];
#pragma unroll
            for (int n = 0; n < NQ; n++) {
                const float4 t4 = *(const float4*)&xs[ci][tl * 4 * STRIDE + 4 * n];
                qf[4*n+0] = t4.x; qf[4*n+1] = t4.y; qf[4*n+2] = t4.z; qf[4*n+3] = t4.w;
            }
#pragma unroll
            for (int k = 0; k < KW; k++) {
                const float4 wa = *(const float4*)&wl[ci * KW + k][og * 8];
                const float4 wb = *(const float4*)&wl[ci * KW + k][og * 8 + 4];
                float wv[8] = {wa.x, wa.y, wa.z, wa.w, wb.x, wb.y, wb.z, wb.w};
#pragma unroll
                for (int i = 0; i < 8; i++)
#pragma unroll
                    for (int j = 0; j < 4; j++)
                        acc[i][j] = fmaf(wv[i], qf[j * STRIDE + k], acc[i][j]);
            }
        }
        __syncthreads();
    }

    // ---- epilogue: bias, (lrelu), store, (stats) ----
#pragma unroll
    for (int i = 0; i < 8; i++) {
        int o = og * 8 + i;
        float bv = bias[o];
        float tmp[4];
        float s1 = 0.f, s2 = 0.f;
#pragma unroll
        for (int j = 0; j < 4; j++) {
            float v = acc[i][j] + bv;
            if (OUTACT) v = lrelu(v);
            tmp[j] = v;
            if (STATS) { s1 += v; s2 += v * v; }
        }
        float4 vs = {tmp[0], tmp[1], tmp[2], tmp[3]};
        *(float4*)&out[(b * NC + o) * L_out + t0 + tl * 4] = vs;
        if (STATS) {
#pragma unroll
            for (int m = 1; m < 16; m <<= 1) {
                s1 += __shfl_xor(s1, m);
                s2 += __shfl_xor(s2, m);
            }
            if (tl == 0) {
                atomicAdd(&stats[o], s1);
                atomicAdd(&stats[NC + o], s2);
            }
        }
    }
}

// ---------------------------------------------------------------------------
// BatchNorm finalize: stats -> per-channel scale/shift
// ---------------------------------------------------------------------------
__global__ void bn_fin(const float* __restrict__ stats, const float* __restrict__ g,
                       const float* __restrict__ bt, float* __restrict__ scsh, float n)
{
    int c = threadIdx.x;
    float m = stats[c] / n;
    float v = stats[NC + c] / n - m * m;
    float sc = g[c] * rsqrtf(v + 1e-5f);
    scsh[c] = sc;
    scsh[NC + c] = bt[c] - m * sc;
}

// ---------------------------------------------------------------------------
// sal GEMM:  sal[b,h,l] = sum_c W[h,c] * xu[b,c,l] + bias[h]
//  MODE 0: per-batch 2048-bin histogram of monotone keys (4 LDS replicas) +
//          sum of exp(sal)
//  MODE 1: recompute identically, collect (key, h*8192+l) for key >= threshold
// block: 256 thr -> 128 h x 64 l, looping 8 l-chunks; c staged in chunks of 32.
// ---------------------------------------------------------------------------
template<int MODE>
__global__ __launch_bounds__(256) void sal_k(
    const float* __restrict__ xu, const float* __restrict__ W,
    const float* __restrict__ bias,
    unsigned* __restrict__ ghist, float* __restrict__ gsum,
    const unsigned* __restrict__ thrv, unsigned* __restrict__ candcnt,
    unsigned* __restrict__ candK, unsigned* __restrict__ candI)
{
    extern __shared__ char smem[];
    float* xs = (float*)smem;                  // [32][64]
    float* wl = xs + 32 * 64;                  // [32][132]
    unsigned* hrep = (unsigned*)(wl + 32 * 132); // MODE0: [4][2049]
    __shared__ float redbuf[4];

    const int b = blockIdx.z, h0 = blockIdx.y * 128;
    const int tid = threadIdx.x;
    const int og = tid >> 4, tl = tid & 15, lane = tid & 63;

    if (MODE == 0) {
        for (int i = tid; i < 4 * 2049; i += 256) hrep[i] = 0;
    }
    float expsum = 0.f;
    unsigned thrkey = 0;
    if (MODE == 1) thrkey = thrv[b * 2] << 21;

    for (int chunk = 0; chunk < 8; chunk++) {
        const int l0 = (blockIdx.x * 8 + chunk) * 64;
        float acc[8][4];
#pragma unroll
        for (int i = 0; i < 8; i++)
#pragma unroll
            for (int j = 0; j < 4; j++) acc[i][j] = 0.f;

        for (int cc = 0; cc < NC; cc += 32) {
            for (int idx = tid; idx < 32 * 64; idx += 256)
                xs[idx] = xu[(b * NC + cc + (idx >> 6)) * LFULL + l0 + (idx & 63)];
            for (int idx = tid; idx < 128 * 32; idx += 256) {
                int h = idx >> 5, c = idx & 31;
                wl[c * 132 + h] = W[(h0 + h) * NC + cc + c];
            }
            __syncthreads();
#pragma unroll 4
            for (int ci = 0; ci < 32; ci++) {
                const float4 xq = *(const float4*)&xs[ci * 64 + tl * 4];
                const float4 wa = *(const float4*)&wl[ci * 132 + og * 8];
                const float4 wb = *(const float4*)&wl[ci * 132 + og * 8 + 4];
                float wv[8] = {wa.x, wa.y, wa.z, wa.w, wb.x, wb.y, wb.z, wb.w};
                float xv[4] = {xq.x, xq.y, xq.z, xq.w};
#pragma unroll
                for (int i = 0; i < 8; i++)
#pragma unroll
                    for (int j = 0; j < 4; j++)
                        acc[i][j] = fmaf(wv[i], xv[j], acc[i][j]);
            }
            __syncthreads();
        }
        // epilogue for this l-chunk
#pragma unroll
        for (int i = 0; i < 8; i++) {
            const int h = h0 + og * 8 + i;
            const float bv = bias[h];
#pragma unroll
            for (int j = 0; j < 4; j++) {
                float v = acc[i][j] + bv;
                if (MODE == 0) {
                    expsum += expf(v);
                    unsigned key = monoKey(v);
                    atomicAdd(&hrep[(tid & 3) * 2049 + (key >> 21)], 1u);
                } else {
                    unsigned key = monoKey(v);
                    bool p = key >= thrkey;
                    unsigned long long m = __ballot(p);
                    if (m) {
                        int leader = __ffsll((unsigned long long)m) - 1;
                        int cnt = __popcll(m);
                        unsigned basepos = 0;
                        if (lane == leader) basepos = atomicAdd(&candcnt[b], (unsigned)cnt);
                        basepos = __shfl(basepos, leader);
                        if (p) {
                            int r = __popcll(m & ((1ull << lane) - 1ull));
                            unsigned pos = basepos + (unsigned)r;
                            if (pos < CAP) {
                                int l = l0 + tl * 4 + j;
                                candK[b * CAP + pos] = key;
                                candI[b * CAP + pos] = (unsigned)((h << 13) | l);
                            }
                        }
                    }
                }
            }
        }
    }

    if (MODE == 0) {
        __syncthreads();
        for (int i = tid; i < 2048; i += 256) {
            unsigned s = hrep[i] + hrep[2049 + i] + hrep[2 * 2049 + i] + hrep[3 * 2049 + i];
            if (s) atomicAdd(&ghist[b * 2048 + i], s);
        }
#pragma unroll
        for (int m = 1; m < 64; m <<= 1) expsum += __shfl_xor(expsum, m);
        if (lane == 0) redbuf[tid >> 6] = expsum;
        __syncthreads();
        if (tid == 0) atomicAdd(&gsum[b], redbuf[0] + redbuf[1] + redbuf[2] + redbuf[3]);
    }
}

// ---------------------------------------------------------------------------
// scan: find the histogram bucket containing the K-th largest element
// ---------------------------------------------------------------------------
__global__ void scan_k(const unsigned* __restrict__ ghist, unsigned* __restrict__ thrv)
{
    int b = threadIdx.x;
    if (b >= NB) return;
    unsigned cum = 0;
    int bin;
    for (bin = 2047; bin >= 0; bin--) {
        unsigned c = ghist[b * 2048 + bin];
        if (cum + c >= KSEL) break;
        cum += c;
    }
    if (bin < 0) bin = 0;
    thrv[b * 2]     = (unsigned)bin;   // threshold bucket
    thrv[b * 2 + 1] = KSEL - cum;      // how many needed from within the bucket
}

// ---------------------------------------------------------------------------
// select: exact top-K among candidates via 3-level radix refinement
// ---------------------------------------------------------------------------
__global__ __launch_bounds__(256) void select_k(
    const unsigned* __restrict__ thrv, const unsigned* __restrict__ candcnt,
    const unsigned* __restrict__ candK, const unsigned* __restrict__ candI,
    uint2* __restrict__ selected, unsigned* __restrict__ selcnt)
{
    const int b = blockIdx.x, tid = threadIdx.x;
    __shared__ unsigned h2[2048];
    __shared__ unsigned l2k[2048], l2i[2048];
    __shared__ unsigned sh[8]; // 0:sel_n 1:m2 2:b2 3:need2 4:b3 5:need3 6:tie

    const unsigned bthr = thrv[b * 2], need = thrv[b * 2 + 1];
    const unsigned Nc = min(candcnt[b], (unsigned)CAP);
    const unsigned* kk = candK + b * CAP;
    const unsigned* ii = candI + b * CAP;
    uint2* sel = selected + b * KSEL;

    for (int i = tid; i < 2048; i += 256) h2[i] = 0;
    if (tid < 8) sh[tid] = 0;
    __syncthreads();

    // phase 1: emit strictly-above buckets; histogram mid bits of the bucket
    for (unsigned i = tid; i < Nc; i += 256) {
        unsigned k = kk[i], bin = k >> 21;
        if (bin > bthr) {
            unsigned p = atomicAdd(&sh[0], 1u);
            if (p < KSEL) sel[p] = make_uint2(k, ii[i]);
        } else if (bin == bthr) {
            atomicAdd(&h2[(k >> 10) & 2047], 1u);
        }
    }
    __syncthreads();
    if (tid == 0) {
        unsigned cum = 0; int bin;
        for (bin = 2047; bin >= 0; bin--) {
            unsigned c = h2[bin];
            if (cum + c >= need) break;
            cum += c;
        }
        if (bin < 0) bin = 0;
        sh[2] = (unsigned)bin; sh[3] = need - cum;
    }
    __syncthreads();
    const unsigned b2 = sh[2], need2 = sh[3];

    // phase 2: emit above mid-bucket; gather mid-bucket to LDS
    for (unsigned i = tid; i < Nc; i += 256) {
        unsigned k = kk[i];
        if ((k >> 21) != bthr) continue;
        unsigned hb = (k >> 10) & 2047;
        if (hb > b2) {
            unsigned p = atomicAdd(&sh[0], 1u);
            if (p < KSEL) sel[p] = make_uint2(k, ii[i]);
        } else if (hb == b2) {
            unsigned j = atomicAdd(&sh[1], 1u);
            if (j < 2048) { l2k[j] = k; l2i[j] = ii[i]; }
        }
    }
    __syncthreads();
    const unsigned m2 = min(sh[1], 2048u);

    // phase 3: low 10 bits
    for (int i = tid; i < 1024; i += 256) h2[i] = 0;
    __syncthreads();
    for (unsigned i = tid; i < m2; i += 256) atomicAdd(&h2[l2k[i] & 1023], 1u);
    __syncthreads();
    if (tid == 0) {
        unsigned cum = 0; int bin;
        for (bin = 1023; bin >= 0; bin--) {
            unsigned c = h2[bin];
            if (cum + c >= need2) break;
            cum += c;
        }
        if (bin < 0) bin = 0;
        sh[4] = (unsigned)bin; sh[5] = need2 - cum;
    }
    __syncthreads();
    const unsigned b3 = sh[4], need3 = sh[5];
    for (unsigned i = tid; i < m2; i += 256) {
        unsigned k = l2k[i], lb = k & 1023;
        if (lb > b3) {
            unsigned p = atomicAdd(&sh[0], 1u);
            if (p < KSEL) sel[p] = make_uint2(k, l2i[i]);
        } else if (lb == b3) {
            unsigned t = atomicAdd(&sh[6], 1u);
            if (t < need3) {
                unsigned p = atomicAdd(&sh[0], 1u);
                if (p < KSEL) sel[p] = make_uint2(k, l2i[i]);
            }
        }
    }
    __syncthreads();
    if (tid == 0) selcnt[b] = min(sh[0], (unsigned)KSEL);
}

// ---------------------------------------------------------------------------
// y init (broadcast sb_down bias) and sparse scatter
// ---------------------------------------------------------------------------
__global__ void inity_k(float* __restrict__ y, const float* __restrict__ bias)
{
    int i = blockIdx.x * 256 + threadIdx.x;           // float4 units, 2097152 total
    float bv = bias[(i >> 11) & 127];
    ((float4*)y)[i] = make_float4(bv, bv, bv, bv);
}

__global__ __launch_bounds__(128) void scatter_k(
    const uint2* __restrict__ selected, const unsigned* __restrict__ selcnt,
    const float* __restrict__ gsum, const float* __restrict__ xu,
    const float* __restrict__ upw, const float* __restrict__ upb,
    const float* __restrict__ dww, float* __restrict__ y)
{
    const int b = blockIdx.y, kidx = blockIdx.x;
    if (kidx >= (int)selcnt[b]) return;
    const uint2 s = selected[b * KSEL + kidx];
    const float salv = keyToF(s.x);
    const unsigned idx = s.y;
    const int h = idx >> 13, l = idx & 8191;
    const int t = threadIdx.x;

    float prod = upw[h * NC + t] * xu[(b * NC + t) * LFULL + l];
#pragma unroll
    for (int m = 1; m < 64; m <<= 1) prod += __shfl_xor(prod, m);
    __shared__ float wsum[2];
    if ((t & 63) == 0) wsum[t >> 6] = prod;
    __syncthreads();
    const float sig = wsum[0] + wsum[1] + upb[h];
    const float val = expf(salv) / gsum[b];
    const float g = sig * val;
    atomicAdd(&y[(b * NC + t) * LFULL + l], dww[t * NH + h] * g);
}

// ---------------------------------------------------------------------------
// final BN apply -> d_out
// ---------------------------------------------------------------------------
__global__ void apply_k(const float* __restrict__ in, const float* __restrict__ scsh,
                        float* __restrict__ out)
{
    int i = blockIdx.x * 256 + threadIdx.x;  // 131072 total
    int c = (i >> 7) & 127;
    out[i] = in[i] * scsh[c] + scsh[NC + c];
}

// ---------------------------------------------------------------------------
extern "C" void kernel_launch(void* const* d_in, const int* in_sizes, int n_in,
                              void* d_out, int out_size, void* d_ws, size_t ws_size,
                              hipStream_t stream)
{
    const float* x        = (const float*)d_in[0];
    const float* up_w     = (const float*)d_in[1];
    const float* up_b     = (const float*)d_in[2];
    const float* up_g     = (const float*)d_in[3];
    const float* up_beta  = (const float*)d_in[4];
    const float* up_out_w = (const float*)d_in[5];
    const float* up_out_b = (const float*)d_in[6];
    const float* sb_up_w  = (const float*)d_in[7];
    const float* sb_up_b  = (const float*)d_in[8];
    const float* sal_w    = (const float*)d_in[9];
    const float* sal_b    = (const float*)d_in[10];
    const float* sb_dn_w  = (const float*)d_in[11];
    const float* sb_dn_b  = (const float*)d_in[12];
    const float* dn_w     = (const float*)d_in[13];
    const float* dn_b     = (const float*)d_in[14];
    const float* dn_g     = (const float*)d_in[15];
    const float* dn_beta  = (const float*)d_in[16];

    char* ws = (char*)d_ws;
    float*    stats   = (float*)(ws + 0);          // 9 layers x [sum128|sumsq128]
    float*    scsh    = (float*)(ws + 16384);      // 9 layers x [scale128|shift128]
    unsigned* ghist   = (unsigned*)(ws + 32768);   // 8 x 2048
    float*    gsum    = (float*)(ws + 98304);      // 8
    unsigned* thrv    = (unsigned*)(ws + 98560);   // 8 x 2
    unsigned* candcnt = (unsigned*)(ws + 98816);   // 8
    unsigned* selcnt  = (unsigned*)(ws + 99072);   // 8
    uint2*    selected= (uint2*)(ws + 99328);      // 8 x 512
    unsigned* candK   = (unsigned*)(ws + 132096);  // 8 x CAP
    unsigned* candI   = (unsigned*)(ws + 1180672); // 8 x CAP
    float*    B0      = (float*)(ws + (size_t)(4 << 20));
    float*    B1      = (float*)(ws + (size_t)(4 << 20) + 33554432u);

    hipMemsetAsync(d_ws, 0, 99104, stream);

    // ---- ConvUpsample: 128 -> 8192 frames ----
    int Lc = 128;
    const float* src = x;
    for (int i = 0; i < 6; i++) {
        int Lo = Lc * 2;
        float* dst = (i % 2 == 0) ? B0 : B1;
        dim3 g(Lo / 64, NB);
        if (i == 0)
            conv_k<3,1,1,true,0,false,true><<<g,256,0,stream>>>(
                src, dst, up_w + i*NC*NC*3, up_b + i*NC, nullptr, stats + i*256, Lc, Lo);
        else
            conv_k<3,1,1,true,2,false,true><<<g,256,0,stream>>>(
                src, dst, up_w + i*NC*NC*3, up_b + i*NC, scsh + (i-1)*256, stats + i*256, Lc, Lo);
        bn_fin<<<1,128,0,stream>>>(stats + i*256, up_g + i*NC, up_beta + i*NC,
                                   scsh + i*256, (float)(NB * Lo));
        src = dst; Lc = Lo;
    }
    // final k3 conv (applies block-5 BN+lrelu on read): B1 -> B0 = x_up
    conv_k<3,1,1,false,2,false,false><<<dim3(LFULL/64, NB),256,0,stream>>>(
        src, B0, up_out_w, up_out_b, scsh + 5*256, nullptr, LFULL, LFULL);

    // ---- SparseBottleneck ----
    sal_k<0><<<dim3(16,8,NB),256, (32*64 + 32*132)*4 + 4*2049*4, stream>>>(
        B0, sal_w, sal_b, ghist, gsum, nullptr, nullptr, nullptr, nullptr);
    scan_k<<<1,64,0,stream>>>(ghist, thrv);
    sal_k<1><<<dim3(16,8,NB),256, (32*64 + 32*132)*4, stream>>>(
        B0, sal_w, sal_b, nullptr, nullptr, thrv, candcnt, candK, candI);
    select_k<<<NB,256,0,stream>>>(thrv, candcnt, candK, candI, selected, selcnt);
    inity_k<<<(NB*NC*LFULL/4)/256,256,0,stream>>>(B1, sb_dn_b);
    scatter_k<<<dim3(KSEL,NB),128,0,stream>>>(selected, selcnt, gsum, B0,
                                              sb_up_w, sb_up_b, sb_dn_w, B1);

    // ---- down stack: 8192 -> 128 ----
    conv_k<7,4,3,false,0,true,true><<<dim3(2048/64, NB),256,0,stream>>>(
        B1, B0, dn_w, dn_b, nullptr, stats + 6*256, 8192, 2048);
    bn_fin<<<1,128,0,stream>>>(stats + 6*256, dn_g, dn_beta, scsh + 6*256, (float)(NB*2048));
    conv_k<7,4,3,false,1,true,true><<<dim3(512/64, NB),256,0,stream>>>(
        B0, B1, dn_w + NC*NC*7, dn_b + NC, scsh + 6*256, stats + 7*256, 2048, 512);
    bn_fin<<<1,128,0,stream>>>(stats + 7*256, dn_g + NC, dn_beta + NC, scsh + 7*256, (float)(NB*512));
    conv_k<7,4,3,false,1,true,true><<<dim3(128/64, NB),256,0,stream>>>(
        B1, B0, dn_w + 2*NC*NC*7, dn_b + 2*NC, scsh + 7*256, stats + 8*256, 512, 128);
    bn_fin<<<1,128,0,stream>>>(stats + 8*256, dn_g + 2*NC, dn_beta + 2*NC, scsh + 8*256, (float)(NB*128));

    apply_k<<<(out_size + 255)/256,256,0,stream>>>(B0, scsh + 8*256, (float*)d_out);
}

// Round 2
// 1713.815 us; speedup vs baseline: 1.2978x; 1.2978x over previous
//
#include <hip/hip_runtime.h>
#include <hip/hip_bf16.h>

// ---------------------------------------------------------------------------
// ExpandAndContractBottleneck: up-conv stack -> sparse softmax-topK bottleneck
// -> down-conv stack.  f32 compute path; top-K exactness guaranteed by
// bf16-materialize + margin filter + exact f32 recompute of candidates.
// ---------------------------------------------------------------------------

#define DEV_INLINE __device__ __forceinline__

constexpr int NB   = 8;      // batch
constexpr int NC   = 128;    // channels
constexpr int NH   = 1024;   // hidden channels
constexpr int LFULL= 8192;   // sparse frames
constexpr int KSEL = 512;    // k_sparse
constexpr int CAP  = 32768;  // candidate capacity per batch

DEV_INLINE unsigned monoKey(float f) {
    unsigned u = __float_as_uint(f);
    return (u & 0x80000000u) ? ~u : (u | 0x80000000u);
}
DEV_INLINE float keyToF(unsigned k) {
    unsigned u = (k & 0x80000000u) ? (k ^ 0x80000000u) : ~k;
    return __uint_as_float(u);
}
DEV_INLINE unsigned monoKey16(unsigned u) {   // u = bf16 bits (16)
    return (u & 0x8000u) ? ((~u) & 0xFFFFu) : (u | 0x8000u);
}
DEV_INLINE unsigned bf16r(float f) {          // f32 -> bf16 bits, RNE
    unsigned u = __float_as_uint(f);
    return (u + 0x7FFFu + ((u >> 16) & 1u)) >> 16;
}
DEV_INLINE float lrelu(float v) { return v >= 0.f ? v : 0.2f * v; }

// ---------------------------------------------------------------------------
// Generic conv kernel.  block: 256 thr -> 128 out-ch x (16*TT) positions,
// per-thread 8 oc x TT t.  UPS folds nearest-2x upsample into staging.
// INMODE: 0 raw, 1 BN apply, 2 BN apply + lrelu (applied to the INPUT read).
// OUTACT: lrelu on output.  STATS: per-channel sum/sumsq atomics.
// ---------------------------------------------------------------------------
template<int KW, int STRIDE, int PAD, bool UPS, int INMODE, bool OUTACT, bool STATS, int TT>
__global__ __launch_bounds__(256) void conv_k(
    const float* __restrict__ in, float* __restrict__ out,
    const float* __restrict__ w, const float* __restrict__ bias,
    const float* __restrict__ scsh, float* __restrict__ stats,
    int L_in, int L_out)
{
    constexpr int TW    = 16 * TT;
    constexpr int CC    = (KW == 7) ? 8 : 16;
    constexpr int SPAN0 = TW * STRIDE + KW - 1;
    constexpr int SPAN  = (SPAN0 + 3) & ~3;
    constexpr int WROW  = 132;
    constexpr int NQ    = ((TT - 1) * STRIDE + KW + 3) / 4;

    __shared__ float xs[CC][SPAN];
    __shared__ float wl[CC * KW][WROW];

    const int b   = blockIdx.y;
    const int t0  = blockIdx.x * TW;
    const int tid = threadIdx.x;
    const int og  = tid >> 4;
    const int tl  = tid & 15;
    const int Lc  = UPS ? 2 * L_in : L_in;
    const int p_base = t0 * STRIDE - PAD;

    float acc[8][TT];
#pragma unroll
    for (int i = 0; i < 8; i++)
#pragma unroll
        for (int j = 0; j < TT; j++) acc[i][j] = 0.f;

    for (int cc = 0; cc < NC; cc += CC) {
        for (int idx = tid; idx < CC * SPAN0; idx += 256) {
            int cl = idx / SPAN0, pp = idx - cl * SPAN0;
            int c = cc + cl;
            int p = p_base + pp;
            float v = 0.f;
            if (p >= 0 && p < Lc) {
                int g = UPS ? (p >> 1) : p;
                float r = in[(b * NC + c) * L_in + g];
                if (INMODE > 0) {
                    float t_ = r * scsh[c] + scsh[NC + c];
                    v = (INMODE == 2) ? lrelu(t_) : t_;
                } else v = r;
            }
            xs[cl][pp] = v;
        }
        for (int idx = tid; idx < NC * CC * KW; idx += 256) {
            int o = idx / (CC * KW), r = idx - o * (CC * KW);
            wl[r][o] = w[o * (NC * KW) + cc * KW + r];
        }
        __syncthreads();

#pragma unroll 2
        for (int ci = 0; ci < CC; ci++) {
            float qf[NQ * 4];
#pragma unroll
            for (int n = 0; n < NQ; n++) {
                const float4 t4 = *(const float4*)&xs[ci][tl * TT * STRIDE + 4 * n];
                qf[4*n+0] = t4.x; qf[4*n+1] = t4.y; qf[4*n+2] = t4.z; qf[4*n+3] = t4.w;
            }
#pragma unroll
            for (int k = 0; k < KW; k++) {
                const float4 wa = *(const float4*)&wl[ci * KW + k][og * 8];
                const float4 wb = *(const float4*)&wl[ci * KW + k][og * 8 + 4];
                float wv[8] = {wa.x, wa.y, wa.z, wa.w, wb.x, wb.y, wb.z, wb.w};
#pragma unroll
                for (int i = 0; i < 8; i++)
#pragma unroll
                    for (int j = 0; j < TT; j++)
                        acc[i][j] = fmaf(wv[i], qf[j * STRIDE + k], acc[i][j]);
            }
        }
        __syncthreads();
    }

#pragma unroll
    for (int i = 0; i < 8; i++) {
        int o = og * 8 + i;
        float bv = bias[o];
        float tmp[TT];
        float s1 = 0.f, s2 = 0.f;
#pragma unroll
        for (int j = 0; j < TT; j++) {
            float v = acc[i][j] + bv;
            if (OUTACT) v = lrelu(v);
            tmp[j] = v;
            if (STATS) { s1 += v; s2 += v * v; }
        }
#pragma unroll
        for (int q = 0; q < TT / 4; q++) {
            float4 vs = {tmp[4*q], tmp[4*q+1], tmp[4*q+2], tmp[4*q+3]};
            *(float4*)&out[(b * NC + o) * L_out + t0 + tl * TT + 4 * q] = vs;
        }
        if (STATS) {
#pragma unroll
            for (int m = 1; m < 16; m <<= 1) {
                s1 += __shfl_xor(s1, m);
                s2 += __shfl_xor(s2, m);
            }
            if (tl == 0) {
                atomicAdd(&stats[o], s1);
                atomicAdd(&stats[NC + o], s2);
            }
        }
    }
}

__global__ void bn_fin(const float* __restrict__ stats, const float* __restrict__ g,
                       const float* __restrict__ bt, float* __restrict__ scsh, float n)
{
    int c = threadIdx.x;
    float m = stats[c] / n;
    float v = stats[NC + c] / n - m * m;
    float sc = g[c] * rsqrtf(v + 1e-5f);
    scsh[c] = sc;
    scsh[NC + c] = bt[c] - m * sc;
}

// ---------------------------------------------------------------------------
// NEW PATH pass A: sal GEMM (f32 VALU, 8h x 8l per thread) -> bf16 store +
// per-batch sum(exp).  No histogram here.
// grid (32, 8, 8): l-tile 256 (2 chunks of 128), h-tile 128, batch.
// ---------------------------------------------------------------------------
__global__ __launch_bounds__(256) void salA_k(
    const float* __restrict__ xu, const float* __restrict__ W,
    const float* __restrict__ bias, float* __restrict__ gsum,
    unsigned short* __restrict__ salbf)
{
    __shared__ float xs[32][128];
    __shared__ float wl[32][132];
    __shared__ float redbuf[4];

    const int b = blockIdx.z, h0 = blockIdx.y * 128;
    const int tid = threadIdx.x;
    const int hg = tid >> 4, lg = tid & 15, lane = tid & 63;

    float expsum = 0.f;

    for (int chunk = 0; chunk < 2; chunk++) {
        const int l0 = blockIdx.x * 256 + chunk * 128;
        float acc[8][8];
#pragma unroll
        for (int i = 0; i < 8; i++)
#pragma unroll
            for (int j = 0; j < 8; j++) acc[i][j] = 0.f;

        for (int cc = 0; cc < NC; cc += 32) {
            for (int idx = tid; idx < 1024; idx += 256) {
                int row = idx >> 5, c4 = idx & 31;
                ((float4*)&xs[row][0])[c4] =
                    ((const float4*)&xu[(b * NC + cc + row) * LFULL + l0])[c4];
            }
            for (int idx = tid; idx < 1024; idx += 256) {
                int h = idx >> 3, c4 = idx & 7;
                float4 w4 = ((const float4*)&W[(h0 + h) * NC + cc])[c4];
                wl[c4*4+0][h] = w4.x; wl[c4*4+1][h] = w4.y;
                wl[c4*4+2][h] = w4.z; wl[c4*4+3][h] = w4.w;
            }
            __syncthreads();
#pragma unroll 4
            for (int ci = 0; ci < 32; ci++) {
                const float4 xa = *(const float4*)&xs[ci][lg * 8];
                const float4 xb = *(const float4*)&xs[ci][lg * 8 + 4];
                const float4 wa = *(const float4*)&wl[ci][hg * 8];
                const float4 wb = *(const float4*)&wl[ci][hg * 8 + 4];
                float xv[8] = {xa.x, xa.y, xa.z, xa.w, xb.x, xb.y, xb.z, xb.w};
                float wv[8] = {wa.x, wa.y, wa.z, wa.w, wb.x, wb.y, wb.z, wb.w};
#pragma unroll
                for (int i = 0; i < 8; i++)
#pragma unroll
                    for (int j = 0; j < 8; j++)
                        acc[i][j] = fmaf(wv[i], xv[j], acc[i][j]);
            }
            __syncthreads();
        }
#pragma unroll
        for (int i = 0; i < 8; i++) {
            const int h = h0 + hg * 8 + i;
            const float bv = bias[h];
            unsigned pk[4];
#pragma unroll
            for (int j2 = 0; j2 < 4; j2++) {
                float v0 = acc[i][2*j2] + bv, v1 = acc[i][2*j2+1] + bv;
                expsum += expf(v0) + expf(v1);
                pk[j2] = bf16r(v0) | (bf16r(v1) << 16);
            }
            *((uint4*)&salbf[((size_t)b * NH + h) * LFULL + l0 + lg * 8]) =
                make_uint4(pk[0], pk[1], pk[2], pk[3]);
        }
    }
#pragma unroll
    for (int m = 1; m < 64; m <<= 1) expsum += __shfl_xor(expsum, m);
    if (lane == 0) redbuf[tid >> 6] = expsum;
    __syncthreads();
    if (tid == 0) atomicAdd(&gsum[b], redbuf[0] + redbuf[1] + redbuf[2] + redbuf[3]);
}

// ---------------------------------------------------------------------------
// bf16-key histogram over sal (4096 bins = sign+exp+3 mantissa), per batch.
// ---------------------------------------------------------------------------
__global__ __launch_bounds__(256) void hist_k(
    const unsigned short* __restrict__ salbf, unsigned* __restrict__ ghist)
{
    __shared__ unsigned hh[2][4096];
    const int b = blockIdx.y, tid = threadIdx.x;
    for (int i = tid; i < 8192; i += 256) ((unsigned*)hh)[i] = 0;
    __syncthreads();
    const uint4* p = (const uint4*)(salbf + (size_t)b * NH * LFULL);
    const int base = blockIdx.x * 2048;
    unsigned* myh = hh[tid & 1];
    for (int i = tid; i < 2048; i += 256) {
        uint4 v = p[base + i];
        unsigned wv[4] = {v.x, v.y, v.z, v.w};
#pragma unroll
        for (int wq = 0; wq < 4; wq++) {
            atomicAdd(&myh[monoKey16(wv[wq] & 0xFFFFu) >> 4], 1u);
            atomicAdd(&myh[monoKey16(wv[wq] >> 16) >> 4], 1u);
        }
    }
    __syncthreads();
    for (int i = tid; i < 4096; i += 256) {
        unsigned s = hh[0][i] + hh[1][i];
        if (s) atomicAdd(&ghist[b * 4096 + i], s);
    }
}

// scan: per-batch, find bucket of rank-K, emit (bucket-1) threshold key16.
__global__ __launch_bounds__(256) void scan2_k(
    const unsigned* __restrict__ ghist, unsigned* __restrict__ thrv)
{
    const int b = blockIdx.x, tid = threadIdx.x;
    __shared__ unsigned part[256];
    unsigned s = 0;
#pragma unroll
    for (int i = 0; i < 16; i++) s += ghist[b * 4096 + tid * 16 + i];
    part[tid] = s;
    __syncthreads();
    if (tid == 0) {
        unsigned cum = 0; int ch;
        for (ch = 255; ch >= 0; ch--) {
            if (cum + part[ch] >= KSEL) break;
            cum += part[ch];
        }
        int bin = 0;
        if (ch >= 0) {
            for (bin = ch * 16 + 15; bin > ch * 16; bin--) {
                unsigned c = ghist[b * 4096 + bin];
                if (cum + c >= KSEL) break;
                cum += c;
            }
        }
        int bcol = bin > 0 ? bin - 1 : 0;
        thrv[b * 2] = (unsigned)bcol << 4;   // key16-space threshold
    }
}

// filter: collect flat indices whose bf16 key >= threshold (superset of topK)
__global__ __launch_bounds__(256) void filter_k(
    const unsigned short* __restrict__ salbf, const unsigned* __restrict__ thrv,
    unsigned* __restrict__ candcnt, unsigned* __restrict__ candI)
{
    const int b = blockIdx.y, tid = threadIdx.x;
    const unsigned thr = thrv[b * 2];
    const int lane = tid & 63;
    const uint4* p = (const uint4*)(salbf + (size_t)b * NH * LFULL);
    const int base = blockIdx.x * 2048;
    for (int i = tid; i < 2048; i += 256) {
        uint4 v = p[base + i];
        unsigned wv[4] = {v.x, v.y, v.z, v.w};
        const unsigned ebase = (unsigned)(base + i) * 8u;
#pragma unroll
        for (int wq = 0; wq < 4; wq++) {
#pragma unroll
            for (int hi = 0; hi < 2; hi++) {
                unsigned bits = hi ? (wv[wq] >> 16) : (wv[wq] & 0xFFFFu);
                bool pr = monoKey16(bits) >= thr;
                unsigned long long m = __ballot(pr);
                if (m) {
                    int leader = __ffsll((unsigned long long)m) - 1;
                    int cnt = __popcll(m);
                    unsigned basepos = 0;
                    if (lane == leader) basepos = atomicAdd(&candcnt[b], (unsigned)cnt);
                    basepos = __shfl(basepos, leader);
                    if (pr) {
                        int r = __popcll(m & ((1ull << lane) - 1ull));
                        unsigned pos = basepos + (unsigned)r;
                        if (pos < CAP) candI[b * CAP + pos] = ebase + 2u * wq + hi;
                    }
                }
            }
        }
    }
}

// exact f32 recompute of sal for each candidate -> candK (monotone key)
__global__ __launch_bounds__(128) void recompute_k(
    const unsigned* __restrict__ candcnt, const unsigned* __restrict__ candI,
    const float* __restrict__ xu, const float* __restrict__ W,
    const float* __restrict__ bias, unsigned* __restrict__ candK)
{
    const int b = blockIdx.y;
    const unsigned cnt = min(candcnt[b], (unsigned)CAP);
    const int t = threadIdx.x;
    __shared__ float wsum[2];
    for (unsigned k = blockIdx.x; k < cnt; k += 1024) {
        unsigned e = candI[b * CAP + k];
        int h = e >> 13, l = e & 8191;
        float prod = W[h * NC + t] * xu[(b * NC + t) * LFULL + l];
#pragma unroll
        for (int m = 1; m < 64; m <<= 1) prod += __shfl_xor(prod, m);
        if ((t & 63) == 0) wsum[t >> 6] = prod;
        __syncthreads();
        if (t == 0) candK[b * CAP + k] = monoKey(wsum[0] + wsum[1] + bias[h]);
        __syncthreads();
    }
}

// self-contained exact top-K among candidates (12/10/10-bit radix refine)
__global__ __launch_bounds__(256) void select2_k(
    const unsigned* __restrict__ candcnt, const unsigned* __restrict__ candK,
    const unsigned* __restrict__ candI,
    uint2* __restrict__ selected, unsigned* __restrict__ selcnt)
{
    const int b = blockIdx.x, tid = threadIdx.x;
    __shared__ unsigned h1[4096];
    __shared__ unsigned l2k[2048], l2i[2048];
    __shared__ unsigned part[256];
    __shared__ unsigned sh[8]; // 0:seln 1:m2 2:b1 3:need1 4:b2 5:need2 6:b3|tie 7:need3

    const unsigned Nc = min(candcnt[b], (unsigned)CAP);
    const unsigned* kk = candK + b * CAP;
    const unsigned* ii = candI + b * CAP;
    uint2* sel = selected + b * KSEL;

    for (int i = tid; i < 4096; i += 256) h1[i] = 0;
    if (tid < 8) sh[tid] = 0;
    __syncthreads();
    for (unsigned i = tid; i < Nc; i += 256) atomicAdd(&h1[kk[i] >> 20], 1u);
    __syncthreads();
    {   // scan level 1
        unsigned s = 0;
#pragma unroll
        for (int i = 0; i < 16; i++) s += h1[tid * 16 + i];
        part[tid] = s;
        __syncthreads();
        if (tid == 0) {
            unsigned cum = 0; int ch;
            for (ch = 255; ch >= 0; ch--) { if (cum + part[ch] >= KSEL) break; cum += part[ch]; }
            int bin = 0;
            if (ch >= 0)
                for (bin = ch * 16 + 15; bin > ch * 16; bin--) {
                    unsigned c = h1[bin];
                    if (cum + c >= KSEL) break;
                    cum += c;
                }
            sh[2] = (unsigned)bin; sh[3] = KSEL - cum;
        }
    }
    __syncthreads();
    const unsigned b1 = sh[2], need1 = sh[3];
    for (int i = tid; i < 1024; i += 256) h1[i] = 0;
    __syncthreads();
    // phase 1
    for (unsigned i = tid; i < Nc; i += 256) {
        unsigned k = kk[i], bin = k >> 20;
        if (bin > b1) {
            unsigned p = atomicAdd(&sh[0], 1u);
            if (p < KSEL) sel[p] = make_uint2(k, ii[i]);
        } else if (bin == b1) {
            atomicAdd(&h1[(k >> 10) & 1023], 1u);
        }
    }
    __syncthreads();
    {   // scan level 2 (1024 bins, chunks of 4)
        unsigned s = 0;
#pragma unroll
        for (int i = 0; i < 4; i++) s += h1[tid * 4 + i];
        part[tid] = s;
        __syncthreads();
        if (tid == 0) {
            unsigned cum = 0; int ch;
            for (ch = 255; ch >= 0; ch--) { if (cum + part[ch] >= need1) break; cum += part[ch]; }
            int bin = 0;
            if (ch >= 0)
                for (bin = ch * 4 + 3; bin > ch * 4; bin--) {
                    unsigned c = h1[bin];
                    if (cum + c >= need1) break;
                    cum += c;
                }
            sh[4] = (unsigned)bin; sh[5] = need1 - cum;
        }
    }
    __syncthreads();
    const unsigned b2 = sh[4], need2 = sh[5];
    for (int i = tid; i < 1024; i += 256) h1[i] = 0;
    __syncthreads();
    // phase 2 (also builds level-3 histogram)
    for (unsigned i = tid; i < Nc; i += 256) {
        unsigned k = kk[i];
        if ((k >> 20) != b1) continue;
        unsigned mb = (k >> 10) & 1023;
        if (mb > b2) {
            unsigned p = atomicAdd(&sh[0], 1u);
            if (p < KSEL) sel[p] = make_uint2(k, ii[i]);
        } else if (mb == b2) {
            unsigned j = atomicAdd(&sh[1], 1u);
            if (j < 2048) { l2k[j] = k; l2i[j] = ii[i]; atomicAdd(&h1[k & 1023], 1u); }
        }
    }
    __syncthreads();
    const unsigned m2 = min(sh[1], 2048u);
    {   // scan level 3
        unsigned s = 0;
#pragma unroll
        for (int i = 0; i < 4; i++) s += h1[tid * 4 + i];
        part[tid] = s;
        __syncthreads();
        if (tid == 0) {
            unsigned cum = 0; int ch;
            for (ch = 255; ch >= 0; ch--) { if (cum + part[ch] >= need2) break; cum += part[ch]; }
            int bin = 0;
            if (ch >= 0)
                for (bin = ch * 4 + 3; bin > ch * 4; bin--) {
                    unsigned c = h1[bin];
                    if (cum + c >= need2) break;
                    cum += c;
                }
            sh[6] = (unsigned)bin; sh[7] = need2 - cum;
        }
    }
    __syncthreads();
    const unsigned b3 = sh[6], need3 = sh[7];
    if (tid == 0) sh[1] = 0;  // reuse as tie counter
    __syncthreads();
    for (unsigned i = tid; i < m2; i += 256) {
        unsigned k = l2k[i], lb = k & 1023;
        if (lb > b3) {
            unsigned p = atomicAdd(&sh[0], 1u);
            if (p < KSEL) sel[p] = make_uint2(k, l2i[i]);
        } else if (lb == b3) {
            unsigned t = atomicAdd(&sh[1], 1u);
            if (t < need3) {
                unsigned p = atomicAdd(&sh[0], 1u);
                if (p < KSEL) sel[p] = make_uint2(k, l2i[i]);
            }
        }
    }
    __syncthreads();
    if (tid == 0) selcnt[b] = min(sh[0], (unsigned)KSEL);
}

// ---------------------------------------------------------------------------
// OLD PATH (fallback for small workspace): two-pass sal + global histogram
// ---------------------------------------------------------------------------
template<int MODE>
__global__ __launch_bounds__(256) void sal_k(
    const float* __restrict__ xu, const float* __restrict__ W,
    const float* __restrict__ bias,
    unsigned* __restrict__ ghist, float* __restrict__ gsum,
    const unsigned* __restrict__ thrv, unsigned* __restrict__ candcnt,
    unsigned* __restrict__ candK, unsigned* __restrict__ candI)
{
    extern __shared__ char smem[];
    float* xs = (float*)smem;
    float* wl = xs + 32 * 64;
    unsigned* hrep = (unsigned*)(wl + 32 * 132);
    __shared__ float redbuf[4];

    const int b = blockIdx.z, h0 = blockIdx.y * 128;
    const int tid = threadIdx.x;
    const int og = tid >> 4, tl = tid & 15, lane = tid & 63;

    if (MODE == 0) for (int i = tid; i < 4 * 2049; i += 256) hrep[i] = 0;
    float expsum = 0.f;
    unsigned thrkey = 0;
    if (MODE == 1) thrkey = thrv[0 + b * 2] << 21;

    for (int chunk = 0; chunk < 8; chunk++) {
        const int l0 = (blockIdx.x * 8 + chunk) * 64;
        float acc[8][4];
#pragma unroll
        for (int i = 0; i < 8; i++)
#pragma unroll
            for (int j = 0; j < 4; j++) acc[i][j] = 0.f;
        for (int cc = 0; cc < NC; cc += 32) {
            for (int idx = tid; idx < 32 * 64; idx += 256)
                xs[idx] = xu[(b * NC + cc + (idx >> 6)) * LFULL + l0 + (idx & 63)];
            for (int idx = tid; idx < 128 * 32; idx += 256) {
                int h = idx >> 5, c = idx & 31;
                wl[c * 132 + h] = W[(h0 + h) * NC + cc + c];
            }
            __syncthreads();
#pragma unroll 4
            for (int ci = 0; ci < 32; ci++) {
                const float4 xq = *(const float4*)&xs[ci * 64 + tl * 4];
                const float4 wa = *(const float4*)&wl[ci * 132 + og * 8];
                const float4 wb = *(const float4*)&wl[ci * 132 + og * 8 + 4];
                float wv[8] = {wa.x, wa.y, wa.z, wa.w, wb.x, wb.y, wb.z, wb.w};
                float xv[4] = {xq.x, xq.y, xq.z, xq.w};
#pragma unroll
                for (int i = 0; i < 8; i++)
#pragma unroll
                    for (int j = 0; j < 4; j++)
                        acc[i][j] = fmaf(wv[i], xv[j], acc[i][j]);
            }
            __syncthreads();
        }
#pragma unroll
        for (int i = 0; i < 8; i++) {
            const int h = h0 + og * 8 + i;
            const float bv = bias[h];
#pragma unroll
            for (int j = 0; j < 4; j++) {
                float v = acc[i][j] + bv;
                if (MODE == 0) {
                    expsum += expf(v);
                    atomicAdd(&hrep[(tid & 3) * 2049 + (monoKey(v) >> 21)], 1u);
                } else {
                    unsigned key = monoKey(v);
                    bool p = key >= thrkey;
                    unsigned long long m = __ballot(p);
                    if (m) {
                        int leader = __ffsll((unsigned long long)m) - 1;
                        int cnt = __popcll(m);
                        unsigned basepos = 0;
                        if (lane == leader) basepos = atomicAdd(&candcnt[b], (unsigned)cnt);
                        basepos = __shfl(basepos, leader);
                        if (p) {
                            int r = __popcll(m & ((1ull << lane) - 1ull));
                            unsigned pos = basepos + (unsigned)r;
                            if (pos < CAP) {
                                int l = l0 + tl * 4 + j;
                                candK[b * CAP + pos] = key;
                                candI[b * CAP + pos] = (unsigned)((h << 13) | l);
                            }
                        }
                    }
                }
            }
        }
    }
    if (MODE == 0) {
        __syncthreads();
        for (int i = tid; i < 2048; i += 256) {
            unsigned s = hrep[i] + hrep[2049 + i] + hrep[2 * 2049 + i] + hrep[3 * 2049 + i];
            if (s) atomicAdd(&ghist[b * 2048 + i], s);
        }
#pragma unroll
        for (int m = 1; m < 64; m <<= 1) expsum += __shfl_xor(expsum, m);
        if (lane == 0) redbuf[tid >> 6] = expsum;
        __syncthreads();
        if (tid == 0) atomicAdd(&gsum[b], redbuf[0] + redbuf[1] + redbuf[2] + redbuf[3]);
    }
}

__global__ void scan_k(const unsigned* __restrict__ ghist, unsigned* __restrict__ thrv)
{
    int b = threadIdx.x;
    if (b >= NB) return;
    unsigned cum = 0;
    int bin;
    for (bin = 2047; bin >= 0; bin--) {
        unsigned c = ghist[b * 2048 + bin];
        if (cum + c >= KSEL) break;
        cum += c;
    }
    if (bin < 0) bin = 0;
    thrv[b * 2]     = (unsigned)bin;
    thrv[b * 2 + 1] = KSEL - cum;
}

__global__ __launch_bounds__(256) void select_k(
    const unsigned* __restrict__ thrv, const unsigned* __restrict__ candcnt,
    const unsigned* __restrict__ candK, const unsigned* __restrict__ candI,
    uint2* __restrict__ selected, unsigned* __restrict__ selcnt)
{
    const int b = blockIdx.x, tid = threadIdx.x;
    __shared__ unsigned h2[2048];
    __shared__ unsigned l2k[2048], l2i[2048];
    __shared__ unsigned sh[8];

    const unsigned bthr = thrv[b * 2], need = thrv[b * 2 + 1];
    const unsigned Nc = min(candcnt[b], (unsigned)CAP);
    const unsigned* kk = candK + b * CAP;
    const unsigned* ii = candI + b * CAP;
    uint2* sel = selected + b * KSEL;

    for (int i = tid; i < 2048; i += 256) h2[i] = 0;
    if (tid < 8) sh[tid] = 0;
    __syncthreads();
    for (unsigned i = tid; i < Nc; i += 256) {
        unsigned k = kk[i], bin = k >> 21;
        if (bin > bthr) {
            unsigned p = atomicAdd(&sh[0], 1u);
            if (p < KSEL) sel[p] = make_uint2(k, ii[i]);
        } else if (bin == bthr) atomicAdd(&h2[(k >> 10) & 2047], 1u);
    }
    __syncthreads();
    if (tid == 0) {
        unsigned cum = 0; int bin;
        for (bin = 2047; bin >= 0; bin--) {
            unsigned c = h2[bin];
            if (cum + c >= need) break;
            cum += c;
        }
        if (bin < 0) bin = 0;
        sh[2] = (unsigned)bin; sh[3] = need - cum;
    }
    __syncthreads();
    const unsigned b2 = sh[2], need2 = sh[3];
    for (unsigned i = tid; i < Nc; i += 256) {
        unsigned k = kk[i];
        if ((k >> 21) != bthr) continue;
        unsigned hb = (k >> 10) & 2047;
        if (hb > b2) {
            unsigned p = atomicAdd(&sh[0], 1u);
            if (p < KSEL) sel[p] = make_uint2(k, ii[i]);
        } else if (hb == b2) {
            unsigned j = atomicAdd(&sh[1], 1u);
            if (j < 2048) { l2k[j] = k; l2i[j] = ii[i]; }
        }
    }
    __syncthreads();
    const unsigned m2 = min(sh[1], 2048u);
    for (int i = tid; i < 1024; i += 256) h2[i] = 0;
    __syncthreads();
    for (unsigned i = tid; i < m2; i += 256) atomicAdd(&h2[l2k[i] & 1023], 1u);
    __syncthreads();
    if (tid == 0) {
        unsigned cum = 0; int bin;
        for (bin = 1023; bin >= 0; bin--) {
            unsigned c = h2[bin];
            if (cum + c >= need2) break;
            cum += c;
        }
        if (bin < 0) bin = 0;
        sh[4] = (unsigned)bin; sh[5] = need2 - cum;
    }
    __syncthreads();
    const unsigned b3 = sh[4], need3 = sh[5];
    for (unsigned i = tid; i < m2; i += 256) {
        unsigned k = l2k[i], lb = k & 1023;
        if (lb > b3) {
            unsigned p = atomicAdd(&sh[0], 1u);
            if (p < KSEL) sel[p] = make_uint2(k, l2i[i]);
        } else if (lb == b3) {
            unsigned t = atomicAdd(&sh[6], 1u);
            if (t < need3) {
                unsigned p = atomicAdd(&sh[0], 1u);
                if (p < KSEL) sel[p] = make_uint2(k, l2i[i]);
            }
        }
    }
    __syncthreads();
    if (tid == 0) selcnt[b] = min(sh[0], (unsigned)KSEL);
}

// ---------------------------------------------------------------------------
__global__ void inity_k(float* __restrict__ y, const float* __restrict__ bias)
{
    int i = blockIdx.x * 256 + threadIdx.x;
    float bv = bias[(i >> 11) & 127];
    ((float4*)y)[i] = make_float4(bv, bv, bv, bv);
}

__global__ __launch_bounds__(128) void scatter_k(
    const uint2* __restrict__ selected, const unsigned* __restrict__ selcnt,
    const float* __restrict__ gsum, const float* __restrict__ xu,
    const float* __restrict__ upw, const float* __restrict__ upb,
    const float* __restrict__ dww, float* __restrict__ y)
{
    const int b = blockIdx.y, kidx = blockIdx.x;
    if (kidx >= (int)selcnt[b]) return;
    const uint2 s = selected[b * KSEL + kidx];
    const float salv = keyToF(s.x);
    const unsigned idx = s.y;
    const int h = idx >> 13, l = idx & 8191;
    const int t = threadIdx.x;

    float prod = upw[h * NC + t] * xu[(b * NC + t) * LFULL + l];
#pragma unroll
    for (int m = 1; m < 64; m <<= 1) prod += __shfl_xor(prod, m);
    __shared__ float wsum[2];
    if ((t & 63) == 0) wsum[t >> 6] = prod;
    __syncthreads();
    const float sig = wsum[0] + wsum[1] + upb[h];
    const float val = expf(salv) / gsum[b];
    const float g = sig * val;
    atomicAdd(&y[(b * NC + t) * LFULL + l], dww[t * NH + h] * g);
}

__global__ void apply_k(const float* __restrict__ in, const float* __restrict__ scsh,
                        float* __restrict__ out)
{
    int i = blockIdx.x * 256 + threadIdx.x;
    int c = (i >> 7) & 127;
    out[i] = in[i] * scsh[c] + scsh[NC + c];
}

// ---------------------------------------------------------------------------
extern "C" void kernel_launch(void* const* d_in, const int* in_sizes, int n_in,
                              void* d_out, int out_size, void* d_ws, size_t ws_size,
                              hipStream_t stream)
{
    const float* x        = (const float*)d_in[0];
    const float* up_w     = (const float*)d_in[1];
    const float* up_b     = (const float*)d_in[2];
    const float* up_g     = (const float*)d_in[3];
    const float* up_beta  = (const float*)d_in[4];
    const float* up_out_w = (const float*)d_in[5];
    const float* up_out_b = (const float*)d_in[6];
    const float* sb_up_w  = (const float*)d_in[7];
    const float* sb_up_b  = (const float*)d_in[8];
    const float* sal_w    = (const float*)d_in[9];
    const float* sal_b    = (const float*)d_in[10];
    const float* sb_dn_w  = (const float*)d_in[11];
    const float* sb_dn_b  = (const float*)d_in[12];
    const float* dn_w     = (const float*)d_in[13];
    const float* dn_b     = (const float*)d_in[14];
    const float* dn_g     = (const float*)d_in[15];
    const float* dn_beta  = (const float*)d_in[16];

    char* ws = (char*)d_ws;
    float*          stats    = (float*)(ws + 0);          // 9x256 f32
    float*          scsh     = (float*)(ws + 16384);      // 9x256 f32
    float*          gsum     = (float*)(ws + 32768);      // 8
    unsigned*       thrv     = (unsigned*)(ws + 32800);   // 8x2
    unsigned*       candcnt  = (unsigned*)(ws + 32896);   // 8
    unsigned*       selcnt   = (unsigned*)(ws + 32928);   // 8
    uint2*          selected = (uint2*)(ws + 33024);      // 8x512
    unsigned*       ghist    = (unsigned*)(ws + 65792);   // 8x4096 (old path: 8x2048)
    unsigned*       candK    = (unsigned*)(ws + 196864);  // 8xCAP
    unsigned*       candI    = (unsigned*)(ws + 1245440); // 8xCAP
    float*          B0       = (float*)(ws + 4194304);
    float*          B1       = (float*)(ws + 37748736);
    unsigned short* salbf    = (unsigned short*)(ws + 71303168); // 134MB

    const bool bigws = ws_size >= 205520896ull;

    hipMemsetAsync(d_ws, 0, 33024, stream);
    hipMemsetAsync(ws + 65792, 0, 131072, stream);

    // ---- ConvUpsample: 128 -> 8192 frames ----
    int Lc = 128;
    const float* src = x;
    for (int i = 0; i < 6; i++) {
        int Lo = Lc * 2;
        float* dst = (i % 2 == 0) ? B0 : B1;
        if (i == 0)
            conv_k<3,1,1,true,0,false,true,4><<<dim3(Lo/64, NB),256,0,stream>>>(
                src, dst, up_w, up_b, nullptr, stats, Lc, Lo);
        else if (Lo < 4096)
            conv_k<3,1,1,true,2,false,true,4><<<dim3(Lo/64, NB),256,0,stream>>>(
                src, dst, up_w + i*NC*NC*3, up_b + i*NC, scsh + (i-1)*256, stats + i*256, Lc, Lo);
        else
            conv_k<3,1,1,true,2,false,true,8><<<dim3(Lo/128, NB),256,0,stream>>>(
                src, dst, up_w + i*NC*NC*3, up_b + i*NC, scsh + (i-1)*256, stats + i*256, Lc, Lo);
        bn_fin<<<1,128,0,stream>>>(stats + i*256, up_g + i*NC, up_beta + i*NC,
                                   scsh + i*256, (float)(NB * Lo));
        src = dst; Lc = Lo;
    }
    conv_k<3,1,1,false,2,false,false,8><<<dim3(LFULL/128, NB),256,0,stream>>>(
        src, B0, up_out_w, up_out_b, scsh + 5*256, nullptr, LFULL, LFULL);

    // ---- SparseBottleneck ----
    if (bigws) {
        salA_k<<<dim3(32,8,NB),256,0,stream>>>(B0, sal_w, sal_b, gsum, salbf);
        hist_k<<<dim3(512,NB),256,0,stream>>>(salbf, ghist);
        scan2_k<<<NB,256,0,stream>>>(ghist, thrv);
        filter_k<<<dim3(512,NB),256,0,stream>>>(salbf, thrv, candcnt, candI);
        recompute_k<<<dim3(1024,NB),128,0,stream>>>(candcnt, candI, B0, sal_w, sal_b, candK);
        select2_k<<<NB,256,0,stream>>>(candcnt, candK, candI, selected, selcnt);
    } else {
        sal_k<0><<<dim3(16,8,NB),256, (32*64 + 32*132)*4 + 4*2049*4, stream>>>(
            B0, sal_w, sal_b, ghist, gsum, nullptr, nullptr, nullptr, nullptr);
        scan_k<<<1,64,0,stream>>>(ghist, thrv);
        sal_k<1><<<dim3(16,8,NB),256, (32*64 + 32*132)*4, stream>>>(
            B0, sal_w, sal_b, nullptr, nullptr, thrv, candcnt, candK, candI);
        select_k<<<NB,256,0,stream>>>(thrv, candcnt, candK, candI, selected, selcnt);
    }
    inity_k<<<(NB*NC*LFULL/4)/256,256,0,stream>>>(B1, sb_dn_b);
    scatter_k<<<dim3(KSEL,NB),128,0,stream>>>(selected, selcnt, gsum, B0,
                                              sb_up_w, sb_up_b, sb_dn_w, B1);

    // ---- down stack: 8192 -> 128 ----
    conv_k<7,4,3,false,0,true,true,4><<<dim3(2048/64, NB),256,0,stream>>>(
        B1, B0, dn_w, dn_b, nullptr, stats + 6*256, 8192, 2048);
    bn_fin<<<1,128,0,stream>>>(stats + 6*256, dn_g, dn_beta, scsh + 6*256, (float)(NB*2048));
    conv_k<7,4,3,false,1,true,true,4><<<dim3(512/64, NB),256,0,stream>>>(
        B0, B1, dn_w + NC*NC*7, dn_b + NC, scsh + 6*256, stats + 7*256, 2048, 512);
    bn_fin<<<1,128,0,stream>>>(stats + 7*256, dn_g + NC, dn_beta + NC, scsh + 7*256, (float)(NB*512));
    conv_k<7,4,3,false,1,true,true,4><<<dim3(128/64, NB),256,0,stream>>>(
        B1, B0, dn_w + 2*NC*NC*7, dn_b + 2*NC, scsh + 7*256, stats + 8*256, 512, 128);
    bn_fin<<<1,128,0,stream>>>(stats + 8*256, dn_g + 2*NC, dn_beta + 2*NC, scsh + 8*256, (float)(NB*128));

    apply_k<<<(out_size + 255)/256,256,0,stream>>>(B0, scsh + 8*256, (float*)d_out);
}

// Round 3
// 1586.655 us; speedup vs baseline: 1.4018x; 1.0801x over previous
//
#include <hip/hip_runtime.h>
#include <hip/hip_bf16.h>

// ---------------------------------------------------------------------------
// ExpandAndContractBottleneck: up-conv stack -> sparse softmax-topK bottleneck
// -> down-conv stack.  f32 compute; top-K exactness via bf16-materialize +
// margin filter + exact f32 recompute of candidates.
// R3: conv staging vectorized (float4), BN-finalize folded into consumers.
// ---------------------------------------------------------------------------

#define DEV_INLINE __device__ __forceinline__

constexpr int NB   = 8;      // batch
constexpr int NC   = 128;    // channels
constexpr int NH   = 1024;   // hidden channels
constexpr int LFULL= 8192;   // sparse frames
constexpr int KSEL = 512;    // k_sparse
constexpr int CAP  = 32768;  // candidate capacity per batch

DEV_INLINE unsigned monoKey(float f) {
    unsigned u = __float_as_uint(f);
    return (u & 0x80000000u) ? ~u : (u | 0x80000000u);
}
DEV_INLINE float keyToF(unsigned k) {
    unsigned u = (k & 0x80000000u) ? (k ^ 0x80000000u) : ~k;
    return __uint_as_float(u);
}
DEV_INLINE unsigned monoKey16(unsigned u) {   // u = bf16 bits
    return (u & 0x8000u) ? ((~u) & 0xFFFFu) : (u | 0x8000u);
}
DEV_INLINE unsigned bf16r(float f) {          // f32 -> bf16 bits, RNE
    unsigned u = __float_as_uint(f);
    return (u + 0x7FFFu + ((u >> 16) & 1u)) >> 16;
}
DEV_INLINE float lrelu(float v) { return v >= 0.f ? v : 0.2f * v; }

// ---------------------------------------------------------------------------
// Generic conv kernel.  block: 256 thr -> 128 out-ch x (16*TT) positions,
// per-thread 8 oc x TT t.  UPS folds nearest-2x upsample into staging.
// INMODE: 0 raw, 1 BN apply, 2 BN apply + lrelu  (on the INPUT read; BN
// scale/shift computed per-block from the previous layer's stats).
// OUTACT: lrelu on output.  STATS: per-channel sum/sumsq atomics.
// All global staging loads are aligned float4; alignment offset OFF is a
// compile-time constant (t0*STRIDE multiple of 4/8).
// ---------------------------------------------------------------------------
template<int KW, int STRIDE, int PAD, bool UPS, int INMODE, bool OUTACT, bool STATS, int TT>
__global__ __launch_bounds__(256) void conv_k(
    const float* __restrict__ in, float* __restrict__ out,
    const float* __restrict__ w, const float* __restrict__ bias,
    const float* __restrict__ stp,  // previous-layer stats (INMODE>0)
    const float* __restrict__ gp, const float* __restrict__ btp, float inv_n,
    float* __restrict__ stats, int L_in, int L_out)
{
    constexpr int TW    = 16 * TT;
    constexpr int CC    = (KW == 7) ? 8 : 16;
    constexpr int SPAN0 = TW * STRIDE + KW - 1;
    constexpr int OFF   = (4 - (PAD & 3)) & 3;       // non-UPS lds offset
    constexpr int NCH   = (OFF + SPAN0 + 3) / 4;     // f4 chunks per row
    constexpr int OFF8  = (8 - (PAD & 7)) & 7;       // UPS lds offset
    constexpr int NCH8  = (OFF8 + SPAN0 + 7) / 8;    // 8-wide chunks per row
    constexpr int XROW  = UPS ? (8 * NCH8 + 4) : (4 * NCH + 4);
    constexpr int WROW  = 132;
    constexpr int WQ    = CC * KW / 4;               // f4 per out-channel
    constexpr int XSPAN = (TT - 1) * STRIDE + KW;
    constexpr int OFFX  = UPS ? OFF8 : OFF;

    __shared__ float xs[CC][XROW];
    __shared__ float wl[CC * KW][WROW];
    __shared__ float scs[NC], shs[NC];

    const int b   = blockIdx.y;
    const int t0  = blockIdx.x * TW;
    const int tid = threadIdx.x;
    const int og  = tid >> 4;
    const int tl  = tid & 15;
    const int pb  = t0 * STRIDE - PAD;
    const int pbA = pb - OFF;          // aligned (mult of 4)
    const int ibase = (pb - OFF8) / 2; // UPS: aligned input base (mult of 4)

    if (INMODE > 0) {
        for (int c = tid; c < NC; c += 256) {
            float m  = stp[c] * inv_n;
            float va = stp[NC + c] * inv_n - m * m;
            float sc = gp[c] * rsqrtf(va + 1e-5f);
            scs[c] = sc;
            shs[c] = btp[c] - m * sc;
        }
        __syncthreads();
    }

    float acc[8][TT];
#pragma unroll
    for (int i = 0; i < 8; i++)
#pragma unroll
        for (int j = 0; j < TT; j++) acc[i][j] = 0.f;

    for (int cc = 0; cc < NC; cc += CC) {
        // ---- stage input window (aligned f4 loads; transform; pad zeros) ----
        if (UPS) {
            for (int idx = tid; idx < CC * NCH8; idx += 256) {
                int cl = idx / NCH8, q = idx - cl * NCH8;
                int c = cc + cl;
                int i0 = ibase + 4 * q;
                const float* rowp = in + ((size_t)b * NC + c) * L_in;
                float e[4];
                if (i0 >= 0 && i0 + 3 < L_in) {
                    float4 v = *(const float4*)(rowp + i0);
                    e[0] = v.x; e[1] = v.y; e[2] = v.z; e[3] = v.w;
                    if (INMODE > 0) {
                        float sc = scs[c], sh = shs[c];
#pragma unroll
                        for (int t = 0; t < 4; t++) {
                            float t_ = e[t] * sc + sh;
                            e[t] = (INMODE == 2) ? lrelu(t_) : t_;
                        }
                    }
                } else {
#pragma unroll
                    for (int t = 0; t < 4; t++) {
                        int ii = i0 + t;
                        float v = 0.f;
                        if (ii >= 0 && ii < L_in) {
                            v = rowp[ii];
                            if (INMODE > 0) {
                                float t_ = v * scs[c] + shs[c];
                                v = (INMODE == 2) ? lrelu(t_) : t_;
                            }
                        }
                        e[t] = v;
                    }
                }
                float4 lo = {e[0], e[0], e[1], e[1]};
                float4 hi = {e[2], e[2], e[3], e[3]};
                *(float4*)&xs[cl][8 * q]     = lo;
                *(float4*)&xs[cl][8 * q + 4] = hi;
            }
        } else {
            const int Lc = L_in;
            for (int idx = tid; idx < CC * NCH; idx += 256) {
                int cl = idx / NCH, q = idx - cl * NCH;
                int c = cc + cl;
                int g0 = pbA + 4 * q;
                const float* rowp = in + ((size_t)b * NC + c) * L_in;
                float e[4];
                if (g0 >= 0 && g0 + 3 < Lc) {
                    float4 v = *(const float4*)(rowp + g0);
                    e[0] = v.x; e[1] = v.y; e[2] = v.z; e[3] = v.w;
                    if (INMODE > 0) {
                        float sc = scs[c], sh = shs[c];
#pragma unroll
                        for (int t = 0; t < 4; t++) {
                            float t_ = e[t] * sc + sh;
                            e[t] = (INMODE == 2) ? lrelu(t_) : t_;
                        }
                    }
                } else {
#pragma unroll
                    for (int t = 0; t < 4; t++) {
                        int g = g0 + t;
                        float v = 0.f;
                        if (g >= 0 && g < Lc) {
                            v = rowp[g];
                            if (INMODE > 0) {
                                float t_ = v * scs[c] + shs[c];
                                v = (INMODE == 2) ? lrelu(t_) : t_;
                            }
                        }
                        e[t] = v;
                    }
                }
                float4 v4 = {e[0], e[1], e[2], e[3]};
                *(float4*)&xs[cl][4 * q] = v4;
            }
        }
        // ---- stage weights: f4 load, transposed scalar LDS store ----
        for (int idx = tid; idx < NC * WQ; idx += 256) {
            int o = idx / WQ, u = idx - o * WQ;
            const float4 w4 = *(const float4*)(w + ((size_t)o * NC + cc) * KW + 4 * u);
            int r = 4 * u;
            wl[r][o] = w4.x; wl[r + 1][o] = w4.y;
            wl[r + 2][o] = w4.z; wl[r + 3][o] = w4.w;
        }
        __syncthreads();

#pragma unroll 2
        for (int ci = 0; ci < CC; ci++) {
            float qf[XSPAN];
#pragma unroll
            for (int t = 0; t < XSPAN; t++)
                qf[t] = xs[ci][OFFX + tl * TT * STRIDE + t];
#pragma unroll
            for (int k = 0; k < KW; k++) {
                const float4 wa = *(const float4*)&wl[ci * KW + k][og * 8];
                const float4 wb = *(const float4*)&wl[ci * KW + k][og * 8 + 4];
                float wv[8] = {wa.x, wa.y, wa.z, wa.w, wb.x, wb.y, wb.z, wb.w};
#pragma unroll
                for (int i = 0; i < 8; i++)
#pragma unroll
                    for (int j = 0; j < TT; j++)
                        acc[i][j] = fmaf(wv[i], qf[j * STRIDE + k], acc[i][j]);
            }
        }
        __syncthreads();
    }

    // ---- epilogue: bias, (lrelu), store, (stats) ----
#pragma unroll
    for (int i = 0; i < 8; i++) {
        int o = og * 8 + i;
        float bv = bias[o];
        float tmp[TT];
        float s1 = 0.f, s2 = 0.f;
#pragma unroll
        for (int j = 0; j < TT; j++) {
            float v = acc[i][j] + bv;
            if (OUTACT) v = lrelu(v);
            tmp[j] = v;
            if (STATS) { s1 += v; s2 += v * v; }
        }
#pragma unroll
        for (int q = 0; q < TT / 4; q++) {
            float4 vs = {tmp[4*q], tmp[4*q+1], tmp[4*q+2], tmp[4*q+3]};
            *(float4*)&out[((size_t)b * NC + o) * L_out + t0 + tl * TT + 4 * q] = vs;
        }
        if (STATS) {
#pragma unroll
            for (int m = 1; m < 16; m <<= 1) {
                s1 += __shfl_xor(s1, m);
                s2 += __shfl_xor(s2, m);
            }
            if (tl == 0) {
                atomicAdd(&stats[o], s1);
                atomicAdd(&stats[NC + o], s2);
            }
        }
    }
}

// ---------------------------------------------------------------------------
// sal GEMM (f32 VALU, 8h x 8l per thread) -> bf16 store + per-batch sum(exp).
// ---------------------------------------------------------------------------
__global__ __launch_bounds__(256) void salA_k(
    const float* __restrict__ xu, const float* __restrict__ W,
    const float* __restrict__ bias, float* __restrict__ gsum,
    unsigned short* __restrict__ salbf)
{
    __shared__ float xs[32][128];
    __shared__ float wl[32][132];
    __shared__ float redbuf[4];

    const int b = blockIdx.z, h0 = blockIdx.y * 128;
    const int tid = threadIdx.x;
    const int hg = tid >> 4, lg = tid & 15, lane = tid & 63;

    float expsum = 0.f;

    for (int chunk = 0; chunk < 2; chunk++) {
        const int l0 = blockIdx.x * 256 + chunk * 128;
        float acc[8][8];
#pragma unroll
        for (int i = 0; i < 8; i++)
#pragma unroll
            for (int j = 0; j < 8; j++) acc[i][j] = 0.f;

        for (int cc = 0; cc < NC; cc += 32) {
            for (int idx = tid; idx < 1024; idx += 256) {
                int row = idx >> 5, c4 = idx & 31;
                ((float4*)&xs[row][0])[c4] =
                    ((const float4*)&xu[(b * NC + cc + row) * LFULL + l0])[c4];
            }
            for (int idx = tid; idx < 1024; idx += 256) {
                int h = idx >> 3, c4 = idx & 7;
                float4 w4 = ((const float4*)&W[(h0 + h) * NC + cc])[c4];
                wl[c4*4+0][h] = w4.x; wl[c4*4+1][h] = w4.y;
                wl[c4*4+2][h] = w4.z; wl[c4*4+3][h] = w4.w;
            }
            __syncthreads();
#pragma unroll 4
            for (int ci = 0; ci < 32; ci++) {
                const float4 xa = *(const float4*)&xs[ci][lg * 8];
                const float4 xb = *(const float4*)&xs[ci][lg * 8 + 4];
                const float4 wa = *(const float4*)&wl[ci][hg * 8];
                const float4 wb = *(const float4*)&wl[ci][hg * 8 + 4];
                float xv[8] = {xa.x, xa.y, xa.z, xa.w, xb.x, xb.y, xb.z, xb.w};
                float wv[8] = {wa.x, wa.y, wa.z, wa.w, wb.x, wb.y, wb.z, wb.w};
#pragma unroll
                for (int i = 0; i < 8; i++)
#pragma unroll
                    for (int j = 0; j < 8; j++)
                        acc[i][j] = fmaf(wv[i], xv[j], acc[i][j]);
            }
            __syncthreads();
        }
#pragma unroll
        for (int i = 0; i < 8; i++) {
            const int h = h0 + hg * 8 + i;
            const float bv = bias[h];
            unsigned pk[4];
#pragma unroll
            for (int j2 = 0; j2 < 4; j2++) {
                float v0 = acc[i][2*j2] + bv, v1 = acc[i][2*j2+1] + bv;
                expsum += expf(v0) + expf(v1);
                pk[j2] = bf16r(v0) | (bf16r(v1) << 16);
            }
            *((uint4*)&salbf[((size_t)b * NH + h) * LFULL + l0 + lg * 8]) =
                make_uint4(pk[0], pk[1], pk[2], pk[3]);
        }
    }
#pragma unroll
    for (int m = 1; m < 64; m <<= 1) expsum += __shfl_xor(expsum, m);
    if (lane == 0) redbuf[tid >> 6] = expsum;
    __syncthreads();
    if (tid == 0) atomicAdd(&gsum[b], redbuf[0] + redbuf[1] + redbuf[2] + redbuf[3]);
}

// ---------------------------------------------------------------------------
// bf16-key histogram over sal (4096 bins), per batch.
// ---------------------------------------------------------------------------
__global__ __launch_bounds__(256) void hist_k(
    const unsigned short* __restrict__ salbf, unsigned* __restrict__ ghist)
{
    __shared__ unsigned hh[2][4096];
    const int b = blockIdx.y, tid = threadIdx.x;
    for (int i = tid; i < 8192; i += 256) ((unsigned*)hh)[i] = 0;
    __syncthreads();
    const uint4* p = (const uint4*)(salbf + (size_t)b * NH * LFULL);
    const int base = blockIdx.x * 2048;
    unsigned* myh = hh[tid & 1];
    for (int i = tid; i < 2048; i += 256) {
        uint4 v = p[base + i];
        unsigned wv[4] = {v.x, v.y, v.z, v.w};
#pragma unroll
        for (int wq = 0; wq < 4; wq++) {
            atomicAdd(&myh[monoKey16(wv[wq] & 0xFFFFu) >> 4], 1u);
            atomicAdd(&myh[monoKey16(wv[wq] >> 16) >> 4], 1u);
        }
    }
    __syncthreads();
    for (int i = tid; i < 4096; i += 256) {
        unsigned s = hh[0][i] + hh[1][i];
        if (s) atomicAdd(&ghist[b * 4096 + i], s);
    }
}

// scan: per-batch, find bucket of rank-K, emit (bucket-1) threshold key16.
__global__ __launch_bounds__(256) void scan2_k(
    const unsigned* __restrict__ ghist, unsigned* __restrict__ thrv)
{
    const int b = blockIdx.x, tid = threadIdx.x;
    __shared__ unsigned part[256];
    unsigned s = 0;
#pragma unroll
    for (int i = 0; i < 16; i++) s += ghist[b * 4096 + tid * 16 + i];
    part[tid] = s;
    __syncthreads();
    if (tid == 0) {
        unsigned cum = 0; int ch;
        for (ch = 255; ch >= 0; ch--) {
            if (cum + part[ch] >= KSEL) break;
            cum += part[ch];
        }
        int bin = 0;
        if (ch >= 0) {
            for (bin = ch * 16 + 15; bin > ch * 16; bin--) {
                unsigned c = ghist[b * 4096 + bin];
                if (cum + c >= KSEL) break;
                cum += c;
            }
        }
        int bcol = bin > 0 ? bin - 1 : 0;
        thrv[b * 2] = (unsigned)bcol << 4;   // key16-space threshold
    }
}

// filter: collect flat indices whose bf16 key >= threshold (superset of topK)
__global__ __launch_bounds__(256) void filter_k(
    const unsigned short* __restrict__ salbf, const unsigned* __restrict__ thrv,
    unsigned* __restrict__ candcnt, unsigned* __restrict__ candI)
{
    const int b = blockIdx.y, tid = threadIdx.x;
    const unsigned thr = thrv[b * 2];
    const int lane = tid & 63;
    const uint4* p = (const uint4*)(salbf + (size_t)b * NH * LFULL);
    const int base = blockIdx.x * 2048;
    for (int i = tid; i < 2048; i += 256) {
        uint4 v = p[base + i];
        unsigned wv[4] = {v.x, v.y, v.z, v.w};
        const unsigned ebase = (unsigned)(base + i) * 8u;
#pragma unroll
        for (int wq = 0; wq < 4; wq++) {
#pragma unroll
            for (int hi = 0; hi < 2; hi++) {
                unsigned bits = hi ? (wv[wq] >> 16) : (wv[wq] & 0xFFFFu);
                bool pr = monoKey16(bits) >= thr;
                unsigned long long m = __ballot(pr);
                if (m) {
                    int leader = __ffsll((unsigned long long)m) - 1;
                    int cnt = __popcll(m);
                    unsigned basepos = 0;
                    if (lane == leader) basepos = atomicAdd(&candcnt[b], (unsigned)cnt);
                    basepos = __shfl(basepos, leader);
                    if (pr) {
                        int r = __popcll(m & ((1ull << lane) - 1ull));
                        unsigned pos = basepos + (unsigned)r;
                        if (pos < CAP) candI[b * CAP + pos] = ebase + 2u * wq + hi;
                    }
                }
            }
        }
    }
}

// exact f32 recompute of sal for each candidate -> candK (monotone key)
__global__ __launch_bounds__(128) void recompute_k(
    const unsigned* __restrict__ candcnt, const unsigned* __restrict__ candI,
    const float* __restrict__ xu, const float* __restrict__ W,
    const float* __restrict__ bias, unsigned* __restrict__ candK)
{
    const int b = blockIdx.y;
    const unsigned cnt = min(candcnt[b], (unsigned)CAP);
    const int t = threadIdx.x;
    __shared__ float wsum[2];
    for (unsigned k = blockIdx.x; k < cnt; k += 1024) {
        unsigned e = candI[b * CAP + k];
        int h = e >> 13, l = e & 8191;
        float prod = W[h * NC + t] * xu[(b * NC + t) * LFULL + l];
#pragma unroll
        for (int m = 1; m < 64; m <<= 1) prod += __shfl_xor(prod, m);
        if ((t & 63) == 0) wsum[t >> 6] = prod;
        __syncthreads();
        if (t == 0) candK[b * CAP + k] = monoKey(wsum[0] + wsum[1] + bias[h]);
        __syncthreads();
    }
}

// self-contained exact top-K among candidates (12/10/10-bit radix refine)
__global__ __launch_bounds__(256) void select2_k(
    const unsigned* __restrict__ candcnt, const unsigned* __restrict__ candK,
    const unsigned* __restrict__ candI,
    uint2* __restrict__ selected, unsigned* __restrict__ selcnt)
{
    const int b = blockIdx.x, tid = threadIdx.x;
    __shared__ unsigned h1[4096];
    __shared__ unsigned l2k[2048], l2i[2048];
    __shared__ unsigned part[256];
    __shared__ unsigned sh[8];

    const unsigned Nc = min(candcnt[b], (unsigned)CAP);
    const unsigned* kk = candK + b * CAP;
    const unsigned* ii = candI + b * CAP;
    uint2* sel = selected + b * KSEL;

    for (int i = tid; i < 4096; i += 256) h1[i] = 0;
    if (tid < 8) sh[tid] = 0;
    __syncthreads();
    for (unsigned i = tid; i < Nc; i += 256) atomicAdd(&h1[kk[i] >> 20], 1u);
    __syncthreads();
    {
        unsigned s = 0;
#pragma unroll
        for (int i = 0; i < 16; i++) s += h1[tid * 16 + i];
        part[tid] = s;
        __syncthreads();
        if (tid == 0) {
            unsigned cum = 0; int ch;
            for (ch = 255; ch >= 0; ch--) { if (cum + part[ch] >= KSEL) break; cum += part[ch]; }
            int bin = 0;
            if (ch >= 0)
                for (bin = ch * 16 + 15; bin > ch * 16; bin--) {
                    unsigned c = h1[bin];
                    if (cum + c >= KSEL) break;
                    cum += c;
                }
            sh[2] = (unsigned)bin; sh[3] = KSEL - cum;
        }
    }
    __syncthreads();
    const unsigned b1 = sh[2], need1 = sh[3];
    for (int i = tid; i < 1024; i += 256) h1[i] = 0;
    __syncthreads();
    for (unsigned i = tid; i < Nc; i += 256) {
        unsigned k = kk[i], bin = k >> 20;
        if (bin > b1) {
            unsigned p = atomicAdd(&sh[0], 1u);
            if (p < KSEL) sel[p] = make_uint2(k, ii[i]);
        } else if (bin == b1) {
            atomicAdd(&h1[(k >> 10) & 1023], 1u);
        }
    }
    __syncthreads();
    {
        unsigned s = 0;
#pragma unroll
        for (int i = 0; i < 4; i++) s += h1[tid * 4 + i];
        part[tid] = s;
        __syncthreads();
        if (tid == 0) {
            unsigned cum = 0; int ch;
            for (ch = 255; ch >= 0; ch--) { if (cum + part[ch] >= need1) break; cum += part[ch]; }
            int bin = 0;
            if (ch >= 0)
                for (bin = ch * 4 + 3; bin > ch * 4; bin--) {
                    unsigned c = h1[bin];
                    if (cum + c >= need1) break;
                    cum += c;
                }
            sh[4] = (unsigned)bin; sh[5] = need1 - cum;
        }
    }
    __syncthreads();
    const unsigned b2 = sh[4], need2 = sh[5];
    for (int i = tid; i < 1024; i += 256) h1[i] = 0;
    __syncthreads();
    for (unsigned i = tid; i < Nc; i += 256) {
        unsigned k = kk[i];
        if ((k >> 20) != b1) continue;
        unsigned mb = (k >> 10) & 1023;
        if (mb > b2) {
            unsigned p = atomicAdd(&sh[0], 1u);
            if (p < KSEL) sel[p] = make_uint2(k, ii[i]);
        } else if (mb == b2) {
            unsigned j = atomicAdd(&sh[1], 1u);
            if (j < 2048) { l2k[j] = k; l2i[j] = ii[i]; atomicAdd(&h1[k & 1023], 1u); }
        }
    }
    __syncthreads();
    const unsigned m2 = min(sh[1], 2048u);
    {
        unsigned s = 0;
#pragma unroll
        for (int i = 0; i < 4; i++) s += h1[tid * 4 + i];
        part[tid] = s;
        __syncthreads();
        if (tid == 0) {
            unsigned cum = 0; int ch;
            for (ch = 255; ch >= 0; ch--) { if (cum + part[ch] >= need2) break; cum += part[ch]; }
            int bin = 0;
            if (ch >= 0)
                for (bin = ch * 4 + 3; bin > ch * 4; bin--) {
                    unsigned c = h1[bin];
                    if (cum + c >= need2) break;
                    cum += c;
                }
            sh[6] = (unsigned)bin; sh[7] = need2 - cum;
        }
    }
    __syncthreads();
    const unsigned b3 = sh[6], need3 = sh[7];
    if (tid == 0) sh[1] = 0;
    __syncthreads();
    for (unsigned i = tid; i < m2; i += 256) {
        unsigned k = l2k[i], lb = k & 1023;
        if (lb > b3) {
            unsigned p = atomicAdd(&sh[0], 1u);
            if (p < KSEL) sel[p] = make_uint2(k, l2i[i]);
        } else if (lb == b3) {
            unsigned t = atomicAdd(&sh[1], 1u);
            if (t < need3) {
                unsigned p = atomicAdd(&sh[0], 1u);
                if (p < KSEL) sel[p] = make_uint2(k, l2i[i]);
            }
        }
    }
    __syncthreads();
    if (tid == 0) selcnt[b] = min(sh[0], (unsigned)KSEL);
}

// ---------------------------------------------------------------------------
__global__ void inity_k(float* __restrict__ y, const float* __restrict__ bias)
{
    int i = blockIdx.x * 256 + threadIdx.x;
    float bv = bias[(i >> 11) & 127];
    ((float4*)y)[i] = make_float4(bv, bv, bv, bv);
}

__global__ __launch_bounds__(128) void scatter_k(
    const uint2* __restrict__ selected, const unsigned* __restrict__ selcnt,
    const float* __restrict__ gsum, const float* __restrict__ xu,
    const float* __restrict__ upw, const float* __restrict__ upb,
    const float* __restrict__ dww, float* __restrict__ y)
{
    const int b = blockIdx.y, kidx = blockIdx.x;
    if (kidx >= (int)selcnt[b]) return;
    const uint2 s = selected[b * KSEL + kidx];
    const float salv = keyToF(s.x);
    const unsigned idx = s.y;
    const int h = idx >> 13, l = idx & 8191;
    const int t = threadIdx.x;

    float prod = upw[h * NC + t] * xu[(b * NC + t) * LFULL + l];
#pragma unroll
    for (int m = 1; m < 64; m <<= 1) prod += __shfl_xor(prod, m);
    __shared__ float wsum[2];
    if ((t & 63) == 0) wsum[t >> 6] = prod;
    __syncthreads();
    const float sig = wsum[0] + wsum[1] + upb[h];
    const float val = expf(salv) / gsum[b];
    const float g = sig * val;
    atomicAdd(&y[(b * NC + t) * LFULL + l], dww[t * NH + h] * g);
}

// final BN apply (computes scale/shift from stats itself) -> d_out
__global__ void apply_k(const float* __restrict__ in, const float* __restrict__ stats,
                        const float* __restrict__ g, const float* __restrict__ bt,
                        float* __restrict__ out, float inv_n)
{
    int i = blockIdx.x * 256 + threadIdx.x;  // 131072 total
    int c = (i >> 7) & 127;
    float m  = stats[c] * inv_n;
    float va = stats[NC + c] * inv_n - m * m;
    float sc = g[c] * rsqrtf(va + 1e-5f);
    out[i] = in[i] * sc + (bt[c] - m * sc);
}

// ---------------------------------------------------------------------------
extern "C" void kernel_launch(void* const* d_in, const int* in_sizes, int n_in,
                              void* d_out, int out_size, void* d_ws, size_t ws_size,
                              hipStream_t stream)
{
    const float* x        = (const float*)d_in[0];
    const float* up_w     = (const float*)d_in[1];
    const float* up_b     = (const float*)d_in[2];
    const float* up_g     = (const float*)d_in[3];
    const float* up_beta  = (const float*)d_in[4];
    const float* up_out_w = (const float*)d_in[5];
    const float* up_out_b = (const float*)d_in[6];
    const float* sb_up_w  = (const float*)d_in[7];
    const float* sb_up_b  = (const float*)d_in[8];
    const float* sal_w    = (const float*)d_in[9];
    const float* sal_b    = (const float*)d_in[10];
    const float* sb_dn_w  = (const float*)d_in[11];
    const float* sb_dn_b  = (const float*)d_in[12];
    const float* dn_w     = (const float*)d_in[13];
    const float* dn_b     = (const float*)d_in[14];
    const float* dn_g     = (const float*)d_in[15];
    const float* dn_beta  = (const float*)d_in[16];

    char* ws = (char*)d_ws;
    float*          stats    = (float*)(ws + 0);          // 9x256 f32
    float*          gsum     = (float*)(ws + 32768);      // 8
    unsigned*       thrv     = (unsigned*)(ws + 32800);   // 8x2
    unsigned*       candcnt  = (unsigned*)(ws + 32896);   // 8
    unsigned*       selcnt   = (unsigned*)(ws + 32928);   // 8
    uint2*          selected = (uint2*)(ws + 33024);      // 8x512
    unsigned*       ghist    = (unsigned*)(ws + 65792);   // 8x4096
    unsigned*       candK    = (unsigned*)(ws + 196864);  // 8xCAP
    unsigned*       candI    = (unsigned*)(ws + 1245440); // 8xCAP
    float*          B0       = (float*)(ws + 4194304);
    float*          B1       = (float*)(ws + 37748736);
    unsigned short* salbf    = (unsigned short*)(ws + 71303168); // 134MB

    hipMemsetAsync(d_ws, 0, 33024, stream);
    hipMemsetAsync(ws + 65792, 0, 131072, stream);

    // ---- ConvUpsample: 128 -> 8192 frames ----
    int Lc = 128;
    const float* src = x;
    for (int i = 0; i < 6; i++) {
        int Lo = Lc * 2;
        float* dst = (i % 2 == 0) ? B0 : B1;
        float inv_n = 1.f / (float)(NB * Lc);
        if (i == 0)
            conv_k<3,1,1,true,0,false,true,4><<<dim3(Lo/64, NB),256,0,stream>>>(
                src, dst, up_w, up_b, nullptr, nullptr, nullptr, 0.f, stats, Lc, Lo);
        else if (Lo <= 2048)
            conv_k<3,1,1,true,2,false,true,4><<<dim3(Lo/64, NB),256,0,stream>>>(
                src, dst, up_w + i*NC*NC*3, up_b + i*NC,
                stats + (i-1)*256, up_g + (i-1)*NC, up_beta + (i-1)*NC, inv_n,
                stats + i*256, Lc, Lo);
        else
            conv_k<3,1,1,true,2,false,true,8><<<dim3(Lo/128, NB),256,0,stream>>>(
                src, dst, up_w + i*NC*NC*3, up_b + i*NC,
                stats + (i-1)*256, up_g + (i-1)*NC, up_beta + (i-1)*NC, inv_n,
                stats + i*256, Lc, Lo);
        src = dst; Lc = Lo;
    }
    // final k3 conv (applies block-5 BN+lrelu on read): B1 -> B0 = x_up
    conv_k<3,1,1,false,2,false,false,8><<<dim3(LFULL/128, NB),256,0,stream>>>(
        src, B0, up_out_w, up_out_b,
        stats + 5*256, up_g + 5*NC, up_beta + 5*NC, 1.f/(float)(NB*LFULL),
        nullptr, LFULL, LFULL);

    // ---- SparseBottleneck ----
    salA_k<<<dim3(32,8,NB),256,0,stream>>>(B0, sal_w, sal_b, gsum, salbf);
    hist_k<<<dim3(512,NB),256,0,stream>>>(salbf, ghist);
    scan2_k<<<NB,256,0,stream>>>(ghist, thrv);
    filter_k<<<dim3(512,NB),256,0,stream>>>(salbf, thrv, candcnt, candI);
    recompute_k<<<dim3(1024,NB),128,0,stream>>>(candcnt, candI, B0, sal_w, sal_b, candK);
    select2_k<<<NB,256,0,stream>>>(candcnt, candK, candI, selected, selcnt);
    inity_k<<<(NB*NC*LFULL/4)/256,256,0,stream>>>(B1, sb_dn_b);
    scatter_k<<<dim3(KSEL,NB),128,0,stream>>>(selected, selcnt, gsum, B0,
                                              sb_up_w, sb_up_b, sb_dn_w, B1);

    // ---- down stack: 8192 -> 128 ----
    conv_k<7,4,3,false,0,true,true,4><<<dim3(2048/64, NB),256,0,stream>>>(
        B1, B0, dn_w, dn_b, nullptr, nullptr, nullptr, 0.f,
        stats + 6*256, 8192, 2048);
    conv_k<7,4,3,false,1,true,true,4><<<dim3(512/64, NB),256,0,stream>>>(
        B0, B1, dn_w + NC*NC*7, dn_b + NC,
        stats + 6*256, dn_g, dn_beta, 1.f/(float)(NB*2048),
        stats + 7*256, 2048, 512);
    conv_k<7,4,3,false,1,true,true,4><<<dim3(128/64, NB),256,0,stream>>>(
        B1, B0, dn_w + 2*NC*NC*7, dn_b + 2*NC,
        stats + 7*256, dn_g + NC, dn_beta + NC, 1.f/(float)(NB*512),
        stats + 8*256, 512, 128);

    apply_k<<<(out_size + 255)/256,256,0,stream>>>(
        B0, stats + 8*256, dn_g + 2*NC, dn_beta + 2*NC, (float*)d_out,
        1.f/(float)(NB*128));
}

// Round 4
// 1463.367 us; speedup vs baseline: 1.5199x; 1.0842x over previous
//
#include <hip/hip_runtime.h>
#include <hip/hip_bf16.h>

// ---------------------------------------------------------------------------
// ExpandAndContractBottleneck.  R4: sal GEMM moved to bf16 MFMA (selection
// exactness preserved: bucket-margin filter tolerates ~6% rel err, bf16 path
// gives <1%; final ranking via exact f32 recompute from f32 x_up).
// ---------------------------------------------------------------------------

#define DEV_INLINE __device__ __forceinline__

constexpr int NB   = 8;
constexpr int NC   = 128;
constexpr int NH   = 1024;
constexpr int LFULL= 8192;
constexpr int KSEL = 512;
constexpr int CAP  = 32768;

typedef __attribute__((ext_vector_type(4))) float f32x4;
typedef __attribute__((ext_vector_type(8))) short bf16x8;

DEV_INLINE unsigned monoKey(float f) {
    unsigned u = __float_as_uint(f);
    return (u & 0x80000000u) ? ~u : (u | 0x80000000u);
}
DEV_INLINE float keyToF(unsigned k) {
    unsigned u = (k & 0x80000000u) ? (k ^ 0x80000000u) : ~k;
    return __uint_as_float(u);
}
DEV_INLINE unsigned monoKey16(unsigned u) {
    return (u & 0x8000u) ? ((~u) & 0xFFFFu) : (u | 0x8000u);
}
DEV_INLINE unsigned bf16r(float f) {
    unsigned u = __float_as_uint(f);
    return (u + 0x7FFFu + ((u >> 16) & 1u)) >> 16;
}
DEV_INLINE float lrelu(float v) { return v >= 0.f ? v : 0.2f * v; }

// ---------------------------------------------------------------------------
// Generic conv kernel. block 256 -> 128 oc x (16*TT) positions, 8oc x TT each.
// XPOSE: additionally emit bf16 transposed output xT[b][l][c] (final up conv).
// ---------------------------------------------------------------------------
template<int KW, int STRIDE, int PAD, bool UPS, int INMODE, bool OUTACT, bool STATS, int TT, bool XPOSE>
__global__ __launch_bounds__(256) void conv_k(
    const float* __restrict__ in, float* __restrict__ out,
    const float* __restrict__ w, const float* __restrict__ bias,
    const float* __restrict__ stp,
    const float* __restrict__ gp, const float* __restrict__ btp, float inv_n,
    float* __restrict__ stats, unsigned short* __restrict__ xtout,
    int L_in, int L_out)
{
    constexpr int TW    = 16 * TT;
    constexpr int CC    = (KW == 7) ? 8 : 16;
    constexpr int SPAN0 = TW * STRIDE + KW - 1;
    constexpr int OFF   = (4 - (PAD & 3)) & 3;
    constexpr int NCH   = (OFF + SPAN0 + 3) / 4;
    constexpr int OFF8  = (8 - (PAD & 7)) & 7;
    constexpr int NCH8  = (OFF8 + SPAN0 + 7) / 8;
    constexpr int XROW  = UPS ? (8 * NCH8 + 4) : (4 * NCH + 4);
    constexpr int WROW  = 132;
    constexpr int WQ    = CC * KW / 4;
    constexpr int XSPAN = (TT - 1) * STRIDE + KW;
    constexpr int OFFX  = UPS ? OFF8 : OFF;

    __shared__ float xs[CC][XROW];
    __shared__ float wl[CC * KW][WROW];
    __shared__ float scs[NC], shs[NC];

    const int b   = blockIdx.y;
    const int t0  = blockIdx.x * TW;
    const int tid = threadIdx.x;
    const int og  = tid >> 4;
    const int tl  = tid & 15;
    const int pb  = t0 * STRIDE - PAD;
    const int pbA = pb - OFF;
    const int ibase = (pb - OFF8) / 2;

    if (INMODE > 0) {
        for (int c = tid; c < NC; c += 256) {
            float m  = stp[c] * inv_n;
            float va = stp[NC + c] * inv_n - m * m;
            float sc = gp[c] * rsqrtf(va + 1e-5f);
            scs[c] = sc;
            shs[c] = btp[c] - m * sc;
        }
        __syncthreads();
    }

    float acc[8][TT];
#pragma unroll
    for (int i = 0; i < 8; i++)
#pragma unroll
        for (int j = 0; j < TT; j++) acc[i][j] = 0.f;

    for (int cc = 0; cc < NC; cc += CC) {
        if (UPS) {
            for (int idx = tid; idx < CC * NCH8; idx += 256) {
                int cl = idx / NCH8, q = idx - cl * NCH8;
                int c = cc + cl;
                int i0 = ibase + 4 * q;
                const float* rowp = in + ((size_t)b * NC + c) * L_in;
                float e[4];
                if (i0 >= 0 && i0 + 3 < L_in) {
                    float4 v = *(const float4*)(rowp + i0);
                    e[0] = v.x; e[1] = v.y; e[2] = v.z; e[3] = v.w;
                    if (INMODE > 0) {
                        float sc = scs[c], sh = shs[c];
#pragma unroll
                        for (int t = 0; t < 4; t++) {
                            float t_ = e[t] * sc + sh;
                            e[t] = (INMODE == 2) ? lrelu(t_) : t_;
                        }
                    }
                } else {
#pragma unroll
                    for (int t = 0; t < 4; t++) {
                        int ii = i0 + t;
                        float v = 0.f;
                        if (ii >= 0 && ii < L_in) {
                            v = rowp[ii];
                            if (INMODE > 0) {
                                float t_ = v * scs[c] + shs[c];
                                v = (INMODE == 2) ? lrelu(t_) : t_;
                            }
                        }
                        e[t] = v;
                    }
                }
                float4 lo = {e[0], e[0], e[1], e[1]};
                float4 hi = {e[2], e[2], e[3], e[3]};
                *(float4*)&xs[cl][8 * q]     = lo;
                *(float4*)&xs[cl][8 * q + 4] = hi;
            }
        } else {
            const int Lc = L_in;
            for (int idx = tid; idx < CC * NCH; idx += 256) {
                int cl = idx / NCH, q = idx - cl * NCH;
                int c = cc + cl;
                int g0 = pbA + 4 * q;
                const float* rowp = in + ((size_t)b * NC + c) * L_in;
                float e[4];
                if (g0 >= 0 && g0 + 3 < Lc) {
                    float4 v = *(const float4*)(rowp + g0);
                    e[0] = v.x; e[1] = v.y; e[2] = v.z; e[3] = v.w;
                    if (INMODE > 0) {
                        float sc = scs[c], sh = shs[c];
#pragma unroll
                        for (int t = 0; t < 4; t++) {
                            float t_ = e[t] * sc + sh;
                            e[t] = (INMODE == 2) ? lrelu(t_) : t_;
                        }
                    }
                } else {
#pragma unroll
                    for (int t = 0; t < 4; t++) {
                        int g = g0 + t;
                        float v = 0.f;
                        if (g >= 0 && g < Lc) {
                            v = rowp[g];
                            if (INMODE > 0) {
                                float t_ = v * scs[c] + shs[c];
                                v = (INMODE == 2) ? lrelu(t_) : t_;
                            }
                        }
                        e[t] = v;
                    }
                }
                float4 v4 = {e[0], e[1], e[2], e[3]};
                *(float4*)&xs[cl][4 * q] = v4;
            }
        }
        for (int idx = tid; idx < NC * WQ; idx += 256) {
            int o = idx / WQ, u = idx - o * WQ;
            const float4 w4 = *(const float4*)(w + ((size_t)o * NC + cc) * KW + 4 * u);
            int r = 4 * u;
            wl[r][o] = w4.x; wl[r + 1][o] = w4.y;
            wl[r + 2][o] = w4.z; wl[r + 3][o] = w4.w;
        }
        __syncthreads();

#pragma unroll 2
        for (int ci = 0; ci < CC; ci++) {
            float qf[XSPAN];
#pragma unroll
            for (int t = 0; t < XSPAN; t++)
                qf[t] = xs[ci][OFFX + tl * TT * STRIDE + t];
#pragma unroll
            for (int k = 0; k < KW; k++) {
                const float4 wa = *(const float4*)&wl[ci * KW + k][og * 8];
                const float4 wb = *(const float4*)&wl[ci * KW + k][og * 8 + 4];
                float wv[8] = {wa.x, wa.y, wa.z, wa.w, wb.x, wb.y, wb.z, wb.w};
#pragma unroll
                for (int i = 0; i < 8; i++)
#pragma unroll
                    for (int j = 0; j < TT; j++)
                        acc[i][j] = fmaf(wv[i], qf[j * STRIDE + k], acc[i][j]);
            }
        }
        __syncthreads();
    }

    // ---- epilogue ----
    float tmpm[8][TT];
#pragma unroll
    for (int i = 0; i < 8; i++) {
        int o = og * 8 + i;
        float bv = bias[o];
        float s1 = 0.f, s2 = 0.f;
#pragma unroll
        for (int j = 0; j < TT; j++) {
            float v = acc[i][j] + bv;
            if (OUTACT) v = lrelu(v);
            tmpm[i][j] = v;
            if (STATS) { s1 += v; s2 += v * v; }
        }
        if constexpr ((TT & 3) == 0) {
#pragma unroll
            for (int q = 0; q < TT / 4; q++) {
                float4 vs = {tmpm[i][4*q], tmpm[i][4*q+1], tmpm[i][4*q+2], tmpm[i][4*q+3]};
                *(float4*)&out[((size_t)b * NC + o) * L_out + t0 + tl * TT + 4 * q] = vs;
            }
        } else {
#pragma unroll
            for (int j = 0; j < TT; j++)
                out[((size_t)b * NC + o) * L_out + t0 + tl * TT + j] = tmpm[i][j];
        }
        if (STATS) {
#pragma unroll
            for (int m = 1; m < 16; m <<= 1) {
                s1 += __shfl_xor(s1, m);
                s2 += __shfl_xor(s2, m);
            }
            if (tl == 0) {
                atomicAdd(&stats[o], s1);
                atomicAdd(&stats[NC + o], s2);
            }
        }
    }
    if constexpr (XPOSE) {
#pragma unroll
        for (int j = 0; j < TT; j++) {
            unsigned pk[4];
#pragma unroll
            for (int q = 0; q < 4; q++)
                pk[q] = bf16r(tmpm[2*q][j]) | (bf16r(tmpm[2*q+1][j]) << 16);
            *(uint4*)&xtout[((size_t)b * LFULL + t0 + tl * TT + j) * NC + og * 8] =
                make_uint4(pk[0], pk[1], pk[2], pk[3]);
        }
    }
}

// ---------------------------------------------------------------------------
// cvtW: sal_w f32 [NH][NC] -> bf16
// ---------------------------------------------------------------------------
__global__ __launch_bounds__(256) void cvtW_k(const float* __restrict__ W,
                                              unsigned short* __restrict__ Wbf)
{
    int i = blockIdx.x * 256 + threadIdx.x;   // 16384 tasks of 8 elems
    const float4 a = *(const float4*)&W[i * 8];
    const float4 b = *(const float4*)&W[i * 8 + 4];
    unsigned pk[4];
    pk[0] = bf16r(a.x) | (bf16r(a.y) << 16);
    pk[1] = bf16r(a.z) | (bf16r(a.w) << 16);
    pk[2] = bf16r(b.x) | (bf16r(b.y) << 16);
    pk[3] = bf16r(b.z) | (bf16r(b.w) << 16);
    *(uint4*)&Wbf[i * 8] = make_uint4(pk[0], pk[1], pk[2], pk[3]);
}

// ---------------------------------------------------------------------------
// salM: MFMA bf16 GEMM  sal[b,h,l] = W[h,:].x[:,l] + bias -> bf16 + sum(exp)
// block 256 (4 waves 2x2), tile 128h x 128l, K=128 fully staged (64KB LDS).
// ---------------------------------------------------------------------------
__global__ __launch_bounds__(256) void salM_k(
    const unsigned short* __restrict__ xT,   // [B][L][C] bf16
    const unsigned short* __restrict__ Wbf,  // [H][C] bf16
    const float* __restrict__ bias, float* __restrict__ gsum,
    unsigned short* __restrict__ salbf)
{
    __shared__ unsigned short Als[128 * 128];  // swizzled [h][c]
    __shared__ unsigned short Bls[128 * 128];  // swizzled [l][c]

    const int b  = blockIdx.z;
    const int h0 = blockIdx.y * 128;
    const int l0 = blockIdx.x * 128;
    const int tid = threadIdx.x;
    const int lane = tid & 63;
    const int wid = tid >> 6;
    const int wh = (wid >> 1) * 64;
    const int wl = (wid & 1) * 64;

    {
        const uint4* gA = (const uint4*)(Wbf + (size_t)h0 * NC);
        const uint4* gB = (const uint4*)(xT + ((size_t)b * LFULL + l0) * NC);
        char* cA = (char*)Als; char* cB = (char*)Bls;
        for (int i = tid; i < 2048; i += 256) {
            int row = i >> 4, q = i & 15;
            unsigned sw = (unsigned)(row * 256 + q * 16) ^ (((unsigned)(row & 7)) << 4);
            *(uint4*)(cA + sw) = gA[i];
        }
        for (int i = tid; i < 2048; i += 256) {
            int row = i >> 4, q = i & 15;
            unsigned sw = (unsigned)(row * 256 + q * 16) ^ (((unsigned)(row & 7)) << 4);
            *(uint4*)(cB + sw) = gB[i];
        }
    }
    __syncthreads();

    f32x4 acc[4][4];
#pragma unroll
    for (int i = 0; i < 4; i++)
#pragma unroll
        for (int j = 0; j < 4; j++) acc[i][j] = (f32x4)(0.f);

    const int r15 = lane & 15, g = lane >> 4;
#pragma unroll
    for (int ks = 0; ks < 4; ks++) {
        bf16x8 af[4], bfv[4];
#pragma unroll
        for (int f = 0; f < 4; f++) {
            int rowA = wh + f * 16 + r15;
            unsigned offA = (unsigned)(rowA * 256 + ks * 64 + g * 16)
                          ^ (((unsigned)(rowA & 7)) << 4);
            af[f] = *(const bf16x8*)((const char*)Als + offA);
            int rowB = wl + f * 16 + r15;
            unsigned offB = (unsigned)(rowB * 256 + ks * 64 + g * 16)
                          ^ (((unsigned)(rowB & 7)) << 4);
            bfv[f] = *(const bf16x8*)((const char*)Bls + offB);
        }
#pragma unroll
        for (int i = 0; i < 4; i++)
#pragma unroll
            for (int j = 0; j < 4; j++)
                acc[i][j] = __builtin_amdgcn_mfma_f32_16x16x32_bf16(
                    af[i], bfv[j], acc[i][j], 0, 0, 0);
    }

    // epilogue: bias + exp-sum + bf16 store
    float expsum = 0.f;
#pragma unroll
    for (int i = 0; i < 4; i++) {
#pragma unroll
        for (int r = 0; r < 4; r++) {
            const int h = h0 + wh + i * 16 + g * 4 + r;
            const float bv = bias[h];
            unsigned short* orow = salbf + ((size_t)b * NH + h) * LFULL + l0 + wl;
#pragma unroll
            for (int j = 0; j < 4; j++) {
                float v = acc[i][j][r] + bv;
                expsum += expf(v);
                orow[j * 16 + r15] = (unsigned short)bf16r(v);
            }
        }
    }
#pragma unroll
    for (int m = 1; m < 64; m <<= 1) expsum += __shfl_xor(expsum, m);
    __syncthreads();
    float* red = (float*)Als;
    if (lane == 0) red[wid] = expsum;
    __syncthreads();
    if (tid == 0) atomicAdd(&gsum[b], red[0] + red[1] + red[2] + red[3]);
}

// ---------------------------------------------------------------------------
// bf16-key histogram over sal (4096 bins), per batch.
// ---------------------------------------------------------------------------
__global__ __launch_bounds__(256) void hist_k(
    const unsigned short* __restrict__ salbf, unsigned* __restrict__ ghist)
{
    __shared__ unsigned hh[2][4096];
    const int b = blockIdx.y, tid = threadIdx.x;
    for (int i = tid; i < 8192; i += 256) ((unsigned*)hh)[i] = 0;
    __syncthreads();
    const uint4* p = (const uint4*)(salbf + (size_t)b * NH * LFULL);
    const int base = blockIdx.x * 2048;
    unsigned* myh = hh[tid & 1];
    for (int i = tid; i < 2048; i += 256) {
        uint4 v = p[base + i];
        unsigned wv[4] = {v.x, v.y, v.z, v.w};
#pragma unroll
        for (int wq = 0; wq < 4; wq++) {
            atomicAdd(&myh[monoKey16(wv[wq] & 0xFFFFu) >> 4], 1u);
            atomicAdd(&myh[monoKey16(wv[wq] >> 16) >> 4], 1u);
        }
    }
    __syncthreads();
    for (int i = tid; i < 4096; i += 256) {
        unsigned s = hh[0][i] + hh[1][i];
        if (s) atomicAdd(&ghist[b * 4096 + i], s);
    }
}

__global__ __launch_bounds__(256) void scan2_k(
    const unsigned* __restrict__ ghist, unsigned* __restrict__ thrv)
{
    const int b = blockIdx.x, tid = threadIdx.x;
    __shared__ unsigned part[256];
    unsigned s = 0;
#pragma unroll
    for (int i = 0; i < 16; i++) s += ghist[b * 4096 + tid * 16 + i];
    part[tid] = s;
    __syncthreads();
    if (tid == 0) {
        unsigned cum = 0; int ch;
        for (ch = 255; ch >= 0; ch--) {
            if (cum + part[ch] >= KSEL) break;
            cum += part[ch];
        }
        int bin = 0;
        if (ch >= 0) {
            for (bin = ch * 16 + 15; bin > ch * 16; bin--) {
                unsigned c = ghist[b * 4096 + bin];
                if (cum + c >= KSEL) break;
                cum += c;
            }
        }
        int bcol = bin > 0 ? bin - 1 : 0;
        thrv[b * 2] = (unsigned)bcol << 4;
    }
}

__global__ __launch_bounds__(256) void filter_k(
    const unsigned short* __restrict__ salbf, const unsigned* __restrict__ thrv,
    unsigned* __restrict__ candcnt, unsigned* __restrict__ candI)
{
    const int b = blockIdx.y, tid = threadIdx.x;
    const unsigned thr = thrv[b * 2];
    const int lane = tid & 63;
    const uint4* p = (const uint4*)(salbf + (size_t)b * NH * LFULL);
    const int base = blockIdx.x * 2048;
    for (int i = tid; i < 2048; i += 256) {
        uint4 v = p[base + i];
        unsigned wv[4] = {v.x, v.y, v.z, v.w};
        const unsigned ebase = (unsigned)(base + i) * 8u;
#pragma unroll
        for (int wq = 0; wq < 4; wq++) {
#pragma unroll
            for (int hi = 0; hi < 2; hi++) {
                unsigned bits = hi ? (wv[wq] >> 16) : (wv[wq] & 0xFFFFu);
                bool pr = monoKey16(bits) >= thr;
                unsigned long long m = __ballot(pr);
                if (m) {
                    int leader = __ffsll((unsigned long long)m) - 1;
                    int cnt = __popcll(m);
                    unsigned basepos = 0;
                    if (lane == leader) basepos = atomicAdd(&candcnt[b], (unsigned)cnt);
                    basepos = __shfl(basepos, leader);
                    if (pr) {
                        int r = __popcll(m & ((1ull << lane) - 1ull));
                        unsigned pos = basepos + (unsigned)r;
                        if (pos < CAP) candI[b * CAP + pos] = ebase + 2u * wq + hi;
                    }
                }
            }
        }
    }
}

__global__ __launch_bounds__(128) void recompute_k(
    const unsigned* __restrict__ candcnt, const unsigned* __restrict__ candI,
    const float* __restrict__ xu, const float* __restrict__ W,
    const float* __restrict__ bias, unsigned* __restrict__ candK)
{
    const int b = blockIdx.y;
    const unsigned cnt = min(candcnt[b], (unsigned)CAP);
    const int t = threadIdx.x;
    __shared__ float wsum[2];
    for (unsigned k = blockIdx.x; k < cnt; k += 1024) {
        unsigned e = candI[b * CAP + k];
        int h = e >> 13, l = e & 8191;
        float prod = W[h * NC + t] * xu[(b * NC + t) * LFULL + l];
#pragma unroll
        for (int m = 1; m < 64; m <<= 1) prod += __shfl_xor(prod, m);
        if ((t & 63) == 0) wsum[t >> 6] = prod;
        __syncthreads();
        if (t == 0) candK[b * CAP + k] = monoKey(wsum[0] + wsum[1] + bias[h]);
        __syncthreads();
    }
}

__global__ __launch_bounds__(256) void select2_k(
    const unsigned* __restrict__ candcnt, const unsigned* __restrict__ candK,
    const unsigned* __restrict__ candI,
    uint2* __restrict__ selected, unsigned* __restrict__ selcnt)
{
    const int b = blockIdx.x, tid = threadIdx.x;
    __shared__ unsigned h1[4096];
    __shared__ unsigned l2k[2048], l2i[2048];
    __shared__ unsigned part[256];
    __shared__ unsigned sh[8];

    const unsigned Nc = min(candcnt[b], (unsigned)CAP);
    const unsigned* kk = candK + b * CAP;
    const unsigned* ii = candI + b * CAP;
    uint2* sel = selected + b * KSEL;

    for (int i = tid; i < 4096; i += 256) h1[i] = 0;
    if (tid < 8) sh[tid] = 0;
    __syncthreads();
    for (unsigned i = tid; i < Nc; i += 256) atomicAdd(&h1[kk[i] >> 20], 1u);
    __syncthreads();
    {
        unsigned s = 0;
#pragma unroll
        for (int i = 0; i < 16; i++) s += h1[tid * 16 + i];
        part[tid] = s;
        __syncthreads();
        if (tid == 0) {
            unsigned cum = 0; int ch;
            for (ch = 255; ch >= 0; ch--) { if (cum + part[ch] >= KSEL) break; cum += part[ch]; }
            int bin = 0;
            if (ch >= 0)
                for (bin = ch * 16 + 15; bin > ch * 16; bin--) {
                    unsigned c = h1[bin];
                    if (cum + c >= KSEL) break;
                    cum += c;
                }
            sh[2] = (unsigned)bin; sh[3] = KSEL - cum;
        }
    }
    __syncthreads();
    const unsigned b1 = sh[2], need1 = sh[3];
    for (int i = tid; i < 1024; i += 256) h1[i] = 0;
    __syncthreads();
    for (unsigned i = tid; i < Nc; i += 256) {
        unsigned k = kk[i], bin = k >> 20;
        if (bin > b1) {
            unsigned p = atomicAdd(&sh[0], 1u);
            if (p < KSEL) sel[p] = make_uint2(k, ii[i]);
        } else if (bin == b1) {
            atomicAdd(&h1[(k >> 10) & 1023], 1u);
        }
    }
    __syncthreads();
    {
        unsigned s = 0;
#pragma unroll
        for (int i = 0; i < 4; i++) s += h1[tid * 4 + i];
        part[tid] = s;
        __syncthreads();
        if (tid == 0) {
            unsigned cum = 0; int ch;
            for (ch = 255; ch >= 0; ch--) { if (cum + part[ch] >= need1) break; cum += part[ch]; }
            int bin = 0;
            if (ch >= 0)
                for (bin = ch * 4 + 3; bin > ch * 4; bin--) {
                    unsigned c = h1[bin];
                    if (cum + c >= need1) break;
                    cum += c;
                }
            sh[4] = (unsigned)bin; sh[5] = need1 - cum;
        }
    }
    __syncthreads();
    const unsigned b2 = sh[4], need2 = sh[5];
    for (int i = tid; i < 1024; i += 256) h1[i] = 0;
    __syncthreads();
    for (unsigned i = tid; i < Nc; i += 256) {
        unsigned k = kk[i];
        if ((k >> 20) != b1) continue;
        unsigned mb = (k >> 10) & 1023;
        if (mb > b2) {
            unsigned p = atomicAdd(&sh[0], 1u);
            if (p < KSEL) sel[p] = make_uint2(k, ii[i]);
        } else if (mb == b2) {
            unsigned j = atomicAdd(&sh[1], 1u);
            if (j < 2048) { l2k[j] = k; l2i[j] = ii[i]; atomicAdd(&h1[k & 1023], 1u); }
        }
    }
    __syncthreads();
    const unsigned m2 = min(sh[1], 2048u);
    {
        unsigned s = 0;
#pragma unroll
        for (int i = 0; i < 4; i++) s += h1[tid * 4 + i];
        part[tid] = s;
        __syncthreads();
        if (tid == 0) {
            unsigned cum = 0; int ch;
            for (ch = 255; ch >= 0; ch--) { if (cum + part[ch] >= need2) break; cum += part[ch]; }
            int bin = 0;
            if (ch >= 0)
                for (bin = ch * 4 + 3; bin > ch * 4; bin--) {
                    unsigned c = h1[bin];
                    if (cum + c >= need2) break;
                    cum += c;
                }
            sh[6] = (unsigned)bin; sh[7] = need2 - cum;
        }
    }
    __syncthreads();
    const unsigned b3 = sh[6], need3 = sh[7];
    if (tid == 0) sh[1] = 0;
    __syncthreads();
    for (unsigned i = tid; i < m2; i += 256) {
        unsigned k = l2k[i], lb = k & 1023;
        if (lb > b3) {
            unsigned p = atomicAdd(&sh[0], 1u);
            if (p < KSEL) sel[p] = make_uint2(k, l2i[i]);
        } else if (lb == b3) {
            unsigned t = atomicAdd(&sh[1], 1u);
            if (t < need3) {
                unsigned p = atomicAdd(&sh[0], 1u);
                if (p < KSEL) sel[p] = make_uint2(k, l2i[i]);
            }
        }
    }
    __syncthreads();
    if (tid == 0) selcnt[b] = min(sh[0], (unsigned)KSEL);
}

// ---------------------------------------------------------------------------
__global__ void inity_k(float* __restrict__ y, const float* __restrict__ bias)
{
    int i = blockIdx.x * 256 + threadIdx.x;
    float bv = bias[(i >> 11) & 127];
    ((float4*)y)[i] = make_float4(bv, bv, bv, bv);
}

__global__ __launch_bounds__(128) void scatter_k(
    const uint2* __restrict__ selected, const unsigned* __restrict__ selcnt,
    const float* __restrict__ gsum, const float* __restrict__ xu,
    const float* __restrict__ upw, const float* __restrict__ upb,
    const float* __restrict__ dww, float* __restrict__ y)
{
    const int b = blockIdx.y, kidx = blockIdx.x;
    if (kidx >= (int)selcnt[b]) return;
    const uint2 s = selected[b * KSEL + kidx];
    const float salv = keyToF(s.x);
    const unsigned idx = s.y;
    const int h = idx >> 13, l = idx & 8191;
    const int t = threadIdx.x;

    float prod = upw[h * NC + t] * xu[(b * NC + t) * LFULL + l];
#pragma unroll
    for (int m = 1; m < 64; m <<= 1) prod += __shfl_xor(prod, m);
    __shared__ float wsum[2];
    if ((t & 63) == 0) wsum[t >> 6] = prod;
    __syncthreads();
    const float sig = wsum[0] + wsum[1] + upb[h];
    const float val = expf(salv) / gsum[b];
    const float g = sig * val;
    atomicAdd(&y[(b * NC + t) * LFULL + l], dww[t * NH + h] * g);
}

__global__ void apply_k(const float* __restrict__ in, const float* __restrict__ stats,
                        const float* __restrict__ g, const float* __restrict__ bt,
                        float* __restrict__ out, float inv_n)
{
    int i = blockIdx.x * 256 + threadIdx.x;
    int c = (i >> 7) & 127;
    float m  = stats[c] * inv_n;
    float va = stats[NC + c] * inv_n - m * m;
    float sc = g[c] * rsqrtf(va + 1e-5f);
    out[i] = in[i] * sc + (bt[c] - m * sc);
}

// ---------------------------------------------------------------------------
extern "C" void kernel_launch(void* const* d_in, const int* in_sizes, int n_in,
                              void* d_out, int out_size, void* d_ws, size_t ws_size,
                              hipStream_t stream)
{
    const float* x        = (const float*)d_in[0];
    const float* up_w     = (const float*)d_in[1];
    const float* up_b     = (const float*)d_in[2];
    const float* up_g     = (const float*)d_in[3];
    const float* up_beta  = (const float*)d_in[4];
    const float* up_out_w = (const float*)d_in[5];
    const float* up_out_b = (const float*)d_in[6];
    const float* sb_up_w  = (const float*)d_in[7];
    const float* sb_up_b  = (const float*)d_in[8];
    const float* sal_w    = (const float*)d_in[9];
    const float* sal_b    = (const float*)d_in[10];
    const float* sb_dn_w  = (const float*)d_in[11];
    const float* sb_dn_b  = (const float*)d_in[12];
    const float* dn_w     = (const float*)d_in[13];
    const float* dn_b     = (const float*)d_in[14];
    const float* dn_g     = (const float*)d_in[15];
    const float* dn_beta  = (const float*)d_in[16];

    char* ws = (char*)d_ws;
    float*          stats    = (float*)(ws + 0);          // 9x256 f32
    float*          gsum     = (float*)(ws + 32768);
    unsigned*       thrv     = (unsigned*)(ws + 32800);
    unsigned*       candcnt  = (unsigned*)(ws + 32896);
    unsigned*       selcnt   = (unsigned*)(ws + 32928);
    uint2*          selected = (uint2*)(ws + 33024);
    unsigned*       ghist    = (unsigned*)(ws + 65792);   // 8x4096
    unsigned*       candK    = (unsigned*)(ws + 196864);
    unsigned*       candI    = (unsigned*)(ws + 1245440);
    unsigned short* Wbf      = (unsigned short*)(ws + 2883584); // 256KB
    float*          B0       = (float*)(ws + 4194304);   // 33.5MB  (x_up f32)
    float*          B1       = (float*)(ws + 37748736);  // 33.5MB  (ping/xT bf16)
    unsigned short* xT       = (unsigned short*)(ws + 37748736);
    unsigned short* salbf    = (unsigned short*)(ws + 71303168); // 134MB
    float*          y        = (float*)(ws + 71303168);  // reuses salbf after filter

    hipMemsetAsync(d_ws, 0, 33024, stream);
    hipMemsetAsync(ws + 65792, 0, 131072, stream);

    cvtW_k<<<64,256,0,stream>>>(sal_w, Wbf);

    // ---- ConvUpsample: 128 -> 8192 frames ----
    int Lc = 128;
    const float* src = x;
    for (int i = 0; i < 6; i++) {
        int Lo = Lc * 2;
        float* dst = (i % 2 == 0) ? B0 : B1;
        float inv_n = 1.f / (float)(NB * Lc);
        if (i == 0)
            conv_k<3,1,1,true,0,false,true,2,false><<<dim3(Lo/32, NB),256,0,stream>>>(
                src, dst, up_w, up_b, nullptr, nullptr, nullptr, 0.f, stats, nullptr, Lc, Lo);
        else if (Lo <= 1024)
            conv_k<3,1,1,true,2,false,true,2,false><<<dim3(Lo/32, NB),256,0,stream>>>(
                src, dst, up_w + i*NC*NC*3, up_b + i*NC,
                stats + (i-1)*256, up_g + (i-1)*NC, up_beta + (i-1)*NC, inv_n,
                stats + i*256, nullptr, Lc, Lo);
        else
            conv_k<3,1,1,true,2,false,true,4,false><<<dim3(Lo/64, NB),256,0,stream>>>(
                src, dst, up_w + i*NC*NC*3, up_b + i*NC,
                stats + (i-1)*256, up_g + (i-1)*NC, up_beta + (i-1)*NC, inv_n,
                stats + i*256, nullptr, Lc, Lo);
        src = dst; Lc = Lo;
    }
    // final k3 conv: B1 -> B0 (f32 x_up) + xT (bf16 transposed, into B1 region)
    conv_k<3,1,1,false,2,false,false,4,true><<<dim3(LFULL/64, NB),256,0,stream>>>(
        src, B0, up_out_w, up_out_b,
        stats + 5*256, up_g + 5*NC, up_beta + 5*NC, 1.f/(float)(NB*LFULL),
        nullptr, xT, LFULL, LFULL);

    // ---- SparseBottleneck ----
    salM_k<<<dim3(64,8,NB),256,0,stream>>>(xT, Wbf, sal_b, gsum, salbf);
    hist_k<<<dim3(512,NB),256,0,stream>>>(salbf, ghist);
    scan2_k<<<NB,256,0,stream>>>(ghist, thrv);
    filter_k<<<dim3(512,NB),256,0,stream>>>(salbf, thrv, candcnt, candI);
    recompute_k<<<dim3(1024,NB),128,0,stream>>>(candcnt, candI, B0, sal_w, sal_b, candK);
    select2_k<<<NB,256,0,stream>>>(candcnt, candK, candI, selected, selcnt);
    inity_k<<<(NB*NC*LFULL/4)/256,256,0,stream>>>(y, sb_dn_b);
    scatter_k<<<dim3(KSEL,NB),128,0,stream>>>(selected, selcnt, gsum, B0,
                                              sb_up_w, sb_up_b, sb_dn_w, y);

    // ---- down stack: 8192 -> 128 ----
    conv_k<7,4,3,false,0,true,true,4,false><<<dim3(2048/64, NB),256,0,stream>>>(
        y, B1, dn_w, dn_b, nullptr, nullptr, nullptr, 0.f,
        stats + 6*256, nullptr, 8192, 2048);
    conv_k<7,4,3,false,1,true,true,2,false><<<dim3(512/32, NB),256,0,stream>>>(
        B1, B0, dn_w + NC*NC*7, dn_b + NC,
        stats + 6*256, dn_g, dn_beta, 1.f/(float)(NB*2048),
        stats + 7*256, nullptr, 2048, 512);
    conv_k<7,4,3,false,1,true,true,1,false><<<dim3(128/16, NB),256,0,stream>>>(
        B0, B1, dn_w + 2*NC*NC*7, dn_b + 2*NC,
        stats + 7*256, dn_g + NC, dn_beta + NC, 1.f/(float)(NB*512),
        stats + 8*256, nullptr, 512, 128);

    apply_k<<<(out_size + 255)/256,256,0,stream>>>(
        B1, stats + 8*256, dn_g + 2*NC, dn_beta + 2*NC, (float*)d_out,
        1.f/(float)(NB*128));
}

// Round 5
// 1304.206 us; speedup vs baseline: 1.7054x; 1.1220x over previous
//
#include <hip/hip_runtime.h>
#include <hip/hip_bf16.h>

// ---------------------------------------------------------------------------
// ExpandAndContractBottleneck.  R5: conv restructured (wave-uniform oc,
// 32oc/block, UPS 2x-decimation decomposition); histogram fused into salM.
// ---------------------------------------------------------------------------

#define DEV_INLINE __device__ __forceinline__

constexpr int NB   = 8;
constexpr int NC   = 128;
constexpr int NH   = 1024;
constexpr int LFULL= 8192;
constexpr int KSEL = 512;
constexpr int CAP  = 32768;

typedef __attribute__((ext_vector_type(4))) float f32x4;
typedef __attribute__((ext_vector_type(8))) short bf16x8;

DEV_INLINE unsigned monoKey(float f) {
    unsigned u = __float_as_uint(f);
    return (u & 0x80000000u) ? ~u : (u | 0x80000000u);
}
DEV_INLINE float keyToF(unsigned k) {
    unsigned u = (k & 0x80000000u) ? (k ^ 0x80000000u) : ~k;
    return __uint_as_float(u);
}
DEV_INLINE unsigned monoKey16(unsigned u) {
    return (u & 0x8000u) ? ((~u) & 0xFFFFu) : (u | 0x8000u);
}
DEV_INLINE unsigned bf16r(float f) {
    unsigned u = __float_as_uint(f);
    return (u + 0x7FFFu + ((u >> 16) & 1u)) >> 16;
}
DEV_INLINE float lrelu(float v) { return v >= 0.f ? v : 0.2f * v; }

// ---------------------------------------------------------------------------
// conv2: 256 thr = 4 waves; each wave owns 8 oc (wave-uniform); block covers
// 32 oc (blockIdx.y selects which 32) x 64*TT t-positions.
// UPS: input is ORIGINAL x; nearest-2x upsample + k3 conv decomposed into two
// k2 filters (combo weights staged in LDS).  Thread -> 8oc x TTO outputs.
// INMODE: 0 raw, 1 BN apply, 2 BN+lrelu (on input read).  OUTACT: lrelu out.
// STATS: per-channel sum/sumsq.  XPOSE: also emit bf16 xT[b][l][c].
// ---------------------------------------------------------------------------
template<int KW, int STRIDE, int PAD, bool UPS, int INMODE, bool OUTACT, bool STATS, int TT, bool XPOSE>
__global__ __launch_bounds__(256) void conv2_k(
    const float* __restrict__ in, float* __restrict__ out,
    const float* __restrict__ w, const float* __restrict__ bias,
    const float* __restrict__ stp, const float* __restrict__ gp,
    const float* __restrict__ btp, float inv_n,
    float* __restrict__ stats, unsigned short* __restrict__ xtout,
    int L_in, int L_out)
{
    constexpr int CC    = (KW == 7) ? 8 : 16;
    constexpr int PT    = 64 * TT;                       // t-space tile
    constexpr int TTO   = UPS ? 2 * TT : TT;             // outputs per thread
    constexpr int SPAN  = UPS ? (PT + 2) : ((PT - 1) * STRIDE + KW);
    constexpr int OFF   = UPS ? 3 : ((4 - (PAD & 3)) & 3);
    constexpr int NCH   = (OFF + SPAN + 3) / 4;
    constexpr int XROW  = 4 * NCH + 4;
    constexpr int NWR   = UPS ? 4 : KW;                  // weight rows (combos)
    constexpr int XSPAN = UPS ? (TT + 2) : ((TT - 1) * STRIDE + KW);

    __shared__ float xs[CC][XROW];
    __shared__ float wl[CC][NWR][36];
    __shared__ float scs[NC], shs[NC];

    const int b    = blockIdx.z;
    const int ocb  = blockIdx.y;
    const int t0   = blockIdx.x * PT;
    const int tid  = threadIdx.x;
    const int lane = tid & 63;
    const int wid  = tid >> 6;
    const int oc0  = ocb * 32 + wid * 8;                 // wave-uniform
    const int gb   = UPS ? (t0 - 1) : (t0 * STRIDE - PAD);
    const int gbA  = gb - OFF;

    if (INMODE > 0) {
        for (int c = tid; c < NC; c += 256) {
            float m  = stp[c] * inv_n;
            float va = stp[NC + c] * inv_n - m * m;
            float sc = gp[c] * rsqrtf(va + 1e-5f);
            scs[c] = sc;
            shs[c] = btp[c] - m * sc;
        }
        __syncthreads();
    }

    float acc[8][TTO];
#pragma unroll
    for (int i = 0; i < 8; i++)
#pragma unroll
        for (int j = 0; j < TTO; j++) acc[i][j] = 0.f;

    for (int cc = 0; cc < NC; cc += CC) {
        // ---- stage input (aligned f4, transform, zero pad) ----
        for (int idx = tid; idx < CC * NCH; idx += 256) {
            int cl = idx / NCH, q = idx - cl * NCH;
            int c = cc + cl;
            int g0 = gbA + 4 * q;
            const float* rowp = in + ((size_t)b * NC + c) * L_in;
            float e[4];
            if (g0 >= 0 && g0 + 4 <= L_in) {
                float4 v = *(const float4*)(rowp + g0);
                e[0] = v.x; e[1] = v.y; e[2] = v.z; e[3] = v.w;
                if (INMODE > 0) {
                    float sc = scs[c], sh = shs[c];
#pragma unroll
                    for (int t = 0; t < 4; t++) {
                        float t_ = e[t] * sc + sh;
                        e[t] = (INMODE == 2) ? lrelu(t_) : t_;
                    }
                }
            } else {
#pragma unroll
                for (int t = 0; t < 4; t++) {
                    int g = g0 + t;
                    float v = 0.f;
                    if (g >= 0 && g < L_in) {
                        v = rowp[g];
                        if (INMODE > 0) {
                            float t_ = v * scs[c] + shs[c];
                            v = (INMODE == 2) ? lrelu(t_) : t_;
                        }
                    }
                    e[t] = v;
                }
            }
            float4 v4 = {e[0], e[1], e[2], e[3]};
            *(float4*)&xs[cl][4 * q] = v4;
        }
        // ---- stage weights (this block's 32 oc only) ----
        for (int idx = tid; idx < 32 * CC; idx += 256) {
            int o = idx / CC, c = idx - (idx / CC) * CC;
            const float* wp = w + ((size_t)(ocb * 32 + o) * NC + cc + c) * KW;
            if (UPS) {
                float w0 = wp[0], w1 = wp[1], w2 = wp[2];
                wl[c][0][o] = w0;
                wl[c][1][o] = w1 + w2;
                wl[c][2][o] = w0 + w1;
                wl[c][3][o] = w2;
            } else {
#pragma unroll
                for (int k = 0; k < KW; k++) wl[c][k][o] = wp[k];
            }
        }
        __syncthreads();

#pragma unroll 2
        for (int ci = 0; ci < CC; ci++) {
            float qf[XSPAN];
            const int base = OFF + lane * TT * (UPS ? 1 : STRIDE);
#pragma unroll
            for (int u = 0; u < XSPAN; u++) qf[u] = xs[ci][base + u];
            if (UPS) {
                const float4 a0 = *(const float4*)&wl[ci][0][wid * 8];
                const float4 a1 = *(const float4*)&wl[ci][0][wid * 8 + 4];
                const float4 b0 = *(const float4*)&wl[ci][1][wid * 8];
                const float4 b1 = *(const float4*)&wl[ci][1][wid * 8 + 4];
                const float4 c0 = *(const float4*)&wl[ci][2][wid * 8];
                const float4 c1 = *(const float4*)&wl[ci][2][wid * 8 + 4];
                const float4 d0 = *(const float4*)&wl[ci][3][wid * 8];
                const float4 d1 = *(const float4*)&wl[ci][3][wid * 8 + 4];
                float w0v[8] = {a0.x,a0.y,a0.z,a0.w,a1.x,a1.y,a1.z,a1.w};
                float w12[8] = {b0.x,b0.y,b0.z,b0.w,b1.x,b1.y,b1.z,b1.w};
                float w01[8] = {c0.x,c0.y,c0.z,c0.w,c1.x,c1.y,c1.z,c1.w};
                float w2v[8] = {d0.x,d0.y,d0.z,d0.w,d1.x,d1.y,d1.z,d1.w};
#pragma unroll
                for (int i = 0; i < 8; i++)
#pragma unroll
                    for (int j = 0; j < TT; j++) {
                        acc[i][2*j]   = fmaf(w0v[i], qf[j],   acc[i][2*j]);
                        acc[i][2*j]   = fmaf(w12[i], qf[j+1], acc[i][2*j]);
                        acc[i][2*j+1] = fmaf(w01[i], qf[j+1], acc[i][2*j+1]);
                        acc[i][2*j+1] = fmaf(w2v[i], qf[j+2], acc[i][2*j+1]);
                    }
            } else {
#pragma unroll
                for (int k = 0; k < KW; k++) {
                    const float4 wa = *(const float4*)&wl[ci][k][wid * 8];
                    const float4 wb = *(const float4*)&wl[ci][k][wid * 8 + 4];
                    float wv[8] = {wa.x,wa.y,wa.z,wa.w,wb.x,wb.y,wb.z,wb.w};
#pragma unroll
                    for (int i = 0; i < 8; i++)
#pragma unroll
                        for (int j = 0; j < TT; j++)
                            acc[i][j] = fmaf(wv[i], qf[j * STRIDE + k], acc[i][j]);
                }
            }
        }
        __syncthreads();
    }

    // ---- epilogue ----
    const int po = (UPS ? 2 * t0 : t0) + lane * TTO;
    float tmpm[8][TTO];
#pragma unroll
    for (int i = 0; i < 8; i++) {
        const int o = oc0 + i;
        const float bv = bias[o];
        float s1 = 0.f, s2 = 0.f;
#pragma unroll
        for (int j = 0; j < TTO; j++) {
            float v = acc[i][j] + bv;
            if (OUTACT) v = lrelu(v);
            tmpm[i][j] = v;
            if (STATS) { s1 += v; s2 += v * v; }
        }
        float* orow = out + ((size_t)b * NC + o) * L_out + po;
        if constexpr (TTO == 4) {
            float4 vs = {tmpm[i][0], tmpm[i][1], tmpm[i][2], tmpm[i][3]};
            *(float4*)orow = vs;
        } else if constexpr (TTO == 2) {
            float2 vs = {tmpm[i][0], tmpm[i][1]};
            *(float2*)orow = vs;
        } else {
            orow[0] = tmpm[i][0];
        }
        if (STATS) {
#pragma unroll
            for (int m = 1; m < 64; m <<= 1) {
                s1 += __shfl_xor(s1, m);
                s2 += __shfl_xor(s2, m);
            }
            if (lane == 0) {
                atomicAdd(&stats[o], s1);
                atomicAdd(&stats[NC + o], s2);
            }
        }
    }
    if constexpr (XPOSE) {
#pragma unroll
        for (int j = 0; j < TTO; j++) {
            unsigned pk[4];
#pragma unroll
            for (int q = 0; q < 4; q++)
                pk[q] = bf16r(tmpm[2*q][j]) | (bf16r(tmpm[2*q+1][j]) << 16);
            *(uint4*)&xtout[((size_t)b * LFULL + po + j) * NC + oc0] =
                make_uint4(pk[0], pk[1], pk[2], pk[3]);
        }
    }
}

// ---------------------------------------------------------------------------
// cvtW: sal_w f32 [NH][NC] -> bf16
// ---------------------------------------------------------------------------
__global__ __launch_bounds__(256) void cvtW_k(const float* __restrict__ W,
                                              unsigned short* __restrict__ Wbf)
{
    int i = blockIdx.x * 256 + threadIdx.x;
    const float4 a = *(const float4*)&W[i * 8];
    const float4 b = *(const float4*)&W[i * 8 + 4];
    unsigned pk[4];
    pk[0] = bf16r(a.x) | (bf16r(a.y) << 16);
    pk[1] = bf16r(a.z) | (bf16r(a.w) << 16);
    pk[2] = bf16r(b.x) | (bf16r(b.y) << 16);
    pk[3] = bf16r(b.z) | (bf16r(b.w) << 16);
    *(uint4*)&Wbf[i * 8] = make_uint4(pk[0], pk[1], pk[2], pk[3]);
}

// ---------------------------------------------------------------------------
// salM: MFMA bf16 GEMM + fused bf16-key histogram + sum(exp).
// block 256 (4 waves 2x2), tile 128h x 128l, K=128 staged (64KB LDS).
// ---------------------------------------------------------------------------
__global__ __launch_bounds__(256) void salM_k(
    const unsigned short* __restrict__ xT,   // [B][L][C] bf16
    const unsigned short* __restrict__ Wbf,  // [H][C] bf16
    const float* __restrict__ bias, float* __restrict__ gsum,
    unsigned short* __restrict__ salbf, unsigned* __restrict__ ghist)
{
    __shared__ unsigned short Als[128 * 128];  // swizzled [h][c]; later: hist
    __shared__ unsigned short Bls[128 * 128];  // swizzled [l][c]; later: red

    const int b  = blockIdx.z;
    const int h0 = blockIdx.y * 128;
    const int l0 = blockIdx.x * 128;
    const int tid = threadIdx.x;
    const int lane = tid & 63;
    const int wid = tid >> 6;
    const int wh = (wid >> 1) * 64;
    const int wl = (wid & 1) * 64;

    {
        const uint4* gA = (const uint4*)(Wbf + (size_t)h0 * NC);
        const uint4* gB = (const uint4*)(xT + ((size_t)b * LFULL + l0) * NC);
        char* cA = (char*)Als; char* cB = (char*)Bls;
        for (int i = tid; i < 2048; i += 256) {
            int row = i >> 4, q = i & 15;
            unsigned sw = (unsigned)(row * 256 + q * 16) ^ (((unsigned)(row & 7)) << 4);
            *(uint4*)(cA + sw) = gA[i];
        }
        for (int i = tid; i < 2048; i += 256) {
            int row = i >> 4, q = i & 15;
            unsigned sw = (unsigned)(row * 256 + q * 16) ^ (((unsigned)(row & 7)) << 4);
            *(uint4*)(cB + sw) = gB[i];
        }
    }
    __syncthreads();

    f32x4 acc[4][4];
#pragma unroll
    for (int i = 0; i < 4; i++)
#pragma unroll
        for (int j = 0; j < 4; j++) acc[i][j] = (f32x4)(0.f);

    const int r15 = lane & 15, g = lane >> 4;
#pragma unroll
    for (int ks = 0; ks < 4; ks++) {
        bf16x8 af[4], bfv[4];
#pragma unroll
        for (int f = 0; f < 4; f++) {
            int rowA = wh + f * 16 + r15;
            unsigned offA = (unsigned)(rowA * 256 + ks * 64 + g * 16)
                          ^ (((unsigned)(rowA & 7)) << 4);
            af[f] = *(const bf16x8*)((const char*)Als + offA);
            int rowB = wl + f * 16 + r15;
            unsigned offB = (unsigned)(rowB * 256 + ks * 64 + g * 16)
                          ^ (((unsigned)(rowB & 7)) << 4);
            bfv[f] = *(const bf16x8*)((const char*)Bls + offB);
        }
#pragma unroll
        for (int i = 0; i < 4; i++)
#pragma unroll
            for (int j = 0; j < 4; j++)
                acc[i][j] = __builtin_amdgcn_mfma_f32_16x16x32_bf16(
                    af[i], bfv[j], acc[i][j], 0, 0, 0);
    }

    // ---- epilogue: bias + exp-sum + bf16 store + LDS histogram ----
    __syncthreads();                         // MFMA fragment reads done
    unsigned* lhist = (unsigned*)Als;        // 2 x 4096 replicas (32KB)
    for (int i = tid; i < 8192; i += 256) lhist[i] = 0;
    __syncthreads();

    unsigned* myh = lhist + (tid & 1) * 4096;
    float expsum = 0.f;
#pragma unroll
    for (int i = 0; i < 4; i++) {
#pragma unroll
        for (int r = 0; r < 4; r++) {
            const int h = h0 + wh + i * 16 + g * 4 + r;
            const float bv = bias[h];
            unsigned short* orow = salbf + ((size_t)b * NH + h) * LFULL + l0 + wl;
#pragma unroll
            for (int j = 0; j < 4; j++) {
                float v = acc[i][j][r] + bv;
                expsum += expf(v);
                unsigned bits = bf16r(v);
                orow[j * 16 + r15] = (unsigned short)bits;
                atomicAdd(&myh[monoKey16(bits) >> 4], 1u);
            }
        }
    }
#pragma unroll
    for (int m = 1; m < 64; m <<= 1) expsum += __shfl_xor(expsum, m);
    float* red = (float*)Bls;
    if (lane == 0) red[wid] = expsum;
    __syncthreads();
    for (int i = tid; i < 4096; i += 256) {
        unsigned s = lhist[i] + lhist[4096 + i];
        if (s) atomicAdd(&ghist[b * 4096 + i], s);
    }
    if (tid == 0) atomicAdd(&gsum[b], red[0] + red[1] + red[2] + red[3]);
}

// ---------------------------------------------------------------------------
__global__ __launch_bounds__(256) void scan2_k(
    const unsigned* __restrict__ ghist, unsigned* __restrict__ thrv)
{
    const int b = blockIdx.x, tid = threadIdx.x;
    __shared__ unsigned part[256];
    unsigned s = 0;
#pragma unroll
    for (int i = 0; i < 16; i++) s += ghist[b * 4096 + tid * 16 + i];
    part[tid] = s;
    __syncthreads();
    if (tid == 0) {
        unsigned cum = 0; int ch;
        for (ch = 255; ch >= 0; ch--) {
            if (cum + part[ch] >= KSEL) break;
            cum += part[ch];
        }
        int bin = 0;
        if (ch >= 0) {
            for (bin = ch * 16 + 15; bin > ch * 16; bin--) {
                unsigned c = ghist[b * 4096 + bin];
                if (cum + c >= KSEL) break;
                cum += c;
            }
        }
        int bcol = bin > 0 ? bin - 1 : 0;
        thrv[b * 2] = (unsigned)bcol << 4;
    }
}

__global__ __launch_bounds__(256) void filter_k(
    const unsigned short* __restrict__ salbf, const unsigned* __restrict__ thrv,
    unsigned* __restrict__ candcnt, unsigned* __restrict__ candI)
{
    const int b = blockIdx.y, tid = threadIdx.x;
    const unsigned thr = thrv[b * 2];
    const int lane = tid & 63;
    const uint4* p = (const uint4*)(salbf + (size_t)b * NH * LFULL);
    const int base = blockIdx.x * 2048;
    for (int i = tid; i < 2048; i += 256) {
        uint4 v = p[base + i];
        unsigned wv[4] = {v.x, v.y, v.z, v.w};
        const unsigned ebase = (unsigned)(base + i) * 8u;
#pragma unroll
        for (int wq = 0; wq < 4; wq++) {
#pragma unroll
            for (int hi = 0; hi < 2; hi++) {
                unsigned bits = hi ? (wv[wq] >> 16) : (wv[wq] & 0xFFFFu);
                bool pr = monoKey16(bits) >= thr;
                unsigned long long m = __ballot(pr);
                if (m) {
                    int leader = __ffsll((unsigned long long)m) - 1;
                    int cnt = __popcll(m);
                    unsigned basepos = 0;
                    if (lane == leader) basepos = atomicAdd(&candcnt[b], (unsigned)cnt);
                    basepos = __shfl(basepos, leader);
                    if (pr) {
                        int r = __popcll(m & ((1ull << lane) - 1ull));
                        unsigned pos = basepos + (unsigned)r;
                        if (pos < CAP) candI[b * CAP + pos] = ebase + 2u * wq + hi;
                    }
                }
            }
        }
    }
}

__global__ __launch_bounds__(128) void recompute_k(
    const unsigned* __restrict__ candcnt, const unsigned* __restrict__ candI,
    const float* __restrict__ xu, const float* __restrict__ W,
    const float* __restrict__ bias, unsigned* __restrict__ candK)
{
    const int b = blockIdx.y;
    const unsigned cnt = min(candcnt[b], (unsigned)CAP);
    const int t = threadIdx.x;
    __shared__ float wsum[2];
    for (unsigned k = blockIdx.x; k < cnt; k += 1024) {
        unsigned e = candI[b * CAP + k];
        int h = e >> 13, l = e & 8191;
        float prod = W[h * NC + t] * xu[(b * NC + t) * LFULL + l];
#pragma unroll
        for (int m = 1; m < 64; m <<= 1) prod += __shfl_xor(prod, m);
        if ((t & 63) == 0) wsum[t >> 6] = prod;
        __syncthreads();
        if (t == 0) candK[b * CAP + k] = monoKey(wsum[0] + wsum[1] + bias[h]);
        __syncthreads();
    }
}

__global__ __launch_bounds__(256) void select2_k(
    const unsigned* __restrict__ candcnt, const unsigned* __restrict__ candK,
    const unsigned* __restrict__ candI,
    uint2* __restrict__ selected, unsigned* __restrict__ selcnt)
{
    const int b = blockIdx.x, tid = threadIdx.x;
    __shared__ unsigned h1[4096];
    __shared__ unsigned l2k[2048], l2i[2048];
    __shared__ unsigned part[256];
    __shared__ unsigned sh[8];

    const unsigned Nc = min(candcnt[b], (unsigned)CAP);
    const unsigned* kk = candK + b * CAP;
    const unsigned* ii = candI + b * CAP;
    uint2* sel = selected + b * KSEL;

    for (int i = tid; i < 4096; i += 256) h1[i] = 0;
    if (tid < 8) sh[tid] = 0;
    __syncthreads();
    for (unsigned i = tid; i < Nc; i += 256) atomicAdd(&h1[kk[i] >> 20], 1u);
    __syncthreads();
    {
        unsigned s = 0;
#pragma unroll
        for (int i = 0; i < 16; i++) s += h1[tid * 16 + i];
        part[tid] = s;
        __syncthreads();
        if (tid == 0) {
            unsigned cum = 0; int ch;
            for (ch = 255; ch >= 0; ch--) { if (cum + part[ch] >= KSEL) break; cum += part[ch]; }
            int bin = 0;
            if (ch >= 0)
                for (bin = ch * 16 + 15; bin > ch * 16; bin--) {
                    unsigned c = h1[bin];
                    if (cum + c >= KSEL) break;
                    cum += c;
                }
            sh[2] = (unsigned)bin; sh[3] = KSEL - cum;
        }
    }
    __syncthreads();
    const unsigned b1 = sh[2], need1 = sh[3];
    for (int i = tid; i < 1024; i += 256) h1[i] = 0;
    __syncthreads();
    for (unsigned i = tid; i < Nc; i += 256) {
        unsigned k = kk[i], bin = k >> 20;
        if (bin > b1) {
            unsigned p = atomicAdd(&sh[0], 1u);
            if (p < KSEL) sel[p] = make_uint2(k, ii[i]);
        } else if (bin == b1) {
            atomicAdd(&h1[(k >> 10) & 1023], 1u);
        }
    }
    __syncthreads();
    {
        unsigned s = 0;
#pragma unroll
        for (int i = 0; i < 4; i++) s += h1[tid * 4 + i];
        part[tid] = s;
        __syncthreads();
        if (tid == 0) {
            unsigned cum = 0; int ch;
            for (ch = 255; ch >= 0; ch--) { if (cum + part[ch] >= need1) break; cum += part[ch]; }
            int bin = 0;
            if (ch >= 0)
                for (bin = ch * 4 + 3; bin > ch * 4; bin--) {
                    unsigned c = h1[bin];
                    if (cum + c >= need1) break;
                    cum += c;
                }
            sh[4] = (unsigned)bin; sh[5] = need1 - cum;
        }
    }
    __syncthreads();
    const unsigned b2 = sh[4], need2 = sh[5];
    for (int i = tid; i < 1024; i += 256) h1[i] = 0;
    __syncthreads();
    for (unsigned i = tid; i < Nc; i += 256) {
        unsigned k = kk[i];
        if ((k >> 20) != b1) continue;
        unsigned mb = (k >> 10) & 1023;
        if (mb > b2) {
            unsigned p = atomicAdd(&sh[0], 1u);
            if (p < KSEL) sel[p] = make_uint2(k, ii[i]);
        } else if (mb == b2) {
            unsigned j = atomicAdd(&sh[1], 1u);
            if (j < 2048) { l2k[j] = k; l2i[j] = ii[i]; atomicAdd(&h1[k & 1023], 1u); }
        }
    }
    __syncthreads();
    const unsigned m2 = min(sh[1], 2048u);
    {
        unsigned s = 0;
#pragma unroll
        for (int i = 0; i < 4; i++) s += h1[tid * 4 + i];
        part[tid] = s;
        __syncthreads();
        if (tid == 0) {
            unsigned cum = 0; int ch;
            for (ch = 255; ch >= 0; ch--) { if (cum + part[ch] >= need2) break; cum += part[ch]; }
            int bin = 0;
            if (ch >= 0)
                for (bin = ch * 4 + 3; bin > ch * 4; bin--) {
                    unsigned c = h1[bin];
                    if (cum + c >= need2) break;
                    cum += c;
                }
            sh[6] = (unsigned)bin; sh[7] = need2 - cum;
        }
    }
    __syncthreads();
    const unsigned b3 = sh[6], need3 = sh[7];
    if (tid == 0) sh[1] = 0;
    __syncthreads();
    for (unsigned i = tid; i < m2; i += 256) {
        unsigned k = l2k[i], lb = k & 1023;
        if (lb > b3) {
            unsigned p = atomicAdd(&sh[0], 1u);
            if (p < KSEL) sel[p] = make_uint2(k, l2i[i]);
        } else if (lb == b3) {
            unsigned t = atomicAdd(&sh[1], 1u);
            if (t < need3) {
                unsigned p = atomicAdd(&sh[0], 1u);
                if (p < KSEL) sel[p] = make_uint2(k, l2i[i]);
            }
        }
    }
    __syncthreads();
    if (tid == 0) selcnt[b] = min(sh[0], (unsigned)KSEL);
}

// ---------------------------------------------------------------------------
__global__ void inity_k(float* __restrict__ y, const float* __restrict__ bias)
{
    int i = blockIdx.x * 256 + threadIdx.x;
    float bv = bias[(i >> 11) & 127];
    ((float4*)y)[i] = make_float4(bv, bv, bv, bv);
}

__global__ __launch_bounds__(128) void scatter_k(
    const uint2* __restrict__ selected, const unsigned* __restrict__ selcnt,
    const float* __restrict__ gsum, const float* __restrict__ xu,
    const float* __restrict__ upw, const float* __restrict__ upb,
    const float* __restrict__ dww, float* __restrict__ y)
{
    const int b = blockIdx.y, kidx = blockIdx.x;
    if (kidx >= (int)selcnt[b]) return;
    const uint2 s = selected[b * KSEL + kidx];
    const float salv = keyToF(s.x);
    const unsigned idx = s.y;
    const int h = idx >> 13, l = idx & 8191;
    const int t = threadIdx.x;

    float prod = upw[h * NC + t] * xu[(b * NC + t) * LFULL + l];
#pragma unroll
    for (int m = 1; m < 64; m <<= 1) prod += __shfl_xor(prod, m);
    __shared__ float wsum[2];
    if ((t & 63) == 0) wsum[t >> 6] = prod;
    __syncthreads();
    const float sig = wsum[0] + wsum[1] + upb[h];
    const float val = expf(salv) / gsum[b];
    const float g = sig * val;
    atomicAdd(&y[(b * NC + t) * LFULL + l], dww[t * NH + h] * g);
}

__global__ void apply_k(const float* __restrict__ in, const float* __restrict__ stats,
                        const float* __restrict__ g, const float* __restrict__ bt,
                        float* __restrict__ out, float inv_n)
{
    int i = blockIdx.x * 256 + threadIdx.x;
    int c = (i >> 7) & 127;
    float m  = stats[c] * inv_n;
    float va = stats[NC + c] * inv_n - m * m;
    float sc = g[c] * rsqrtf(va + 1e-5f);
    out[i] = in[i] * sc + (bt[c] - m * sc);
}

// ---------------------------------------------------------------------------
extern "C" void kernel_launch(void* const* d_in, const int* in_sizes, int n_in,
                              void* d_out, int out_size, void* d_ws, size_t ws_size,
                              hipStream_t stream)
{
    const float* x        = (const float*)d_in[0];
    const float* up_w     = (const float*)d_in[1];
    const float* up_b     = (const float*)d_in[2];
    const float* up_g     = (const float*)d_in[3];
    const float* up_beta  = (const float*)d_in[4];
    const float* up_out_w = (const float*)d_in[5];
    const float* up_out_b = (const float*)d_in[6];
    const float* sb_up_w  = (const float*)d_in[7];
    const float* sb_up_b  = (const float*)d_in[8];
    const float* sal_w    = (const float*)d_in[9];
    const float* sal_b    = (const float*)d_in[10];
    const float* sb_dn_w  = (const float*)d_in[11];
    const float* sb_dn_b  = (const float*)d_in[12];
    const float* dn_w     = (const float*)d_in[13];
    const float* dn_b     = (const float*)d_in[14];
    const float* dn_g     = (const float*)d_in[15];
    const float* dn_beta  = (const float*)d_in[16];

    char* ws = (char*)d_ws;
    float*          stats    = (float*)(ws + 0);          // 9x256 f32
    float*          gsum     = (float*)(ws + 32768);
    unsigned*       thrv     = (unsigned*)(ws + 32800);
    unsigned*       candcnt  = (unsigned*)(ws + 32896);
    unsigned*       selcnt   = (unsigned*)(ws + 32928);
    uint2*          selected = (uint2*)(ws + 33024);
    unsigned*       ghist    = (unsigned*)(ws + 65792);   // 8x4096
    unsigned*       candK    = (unsigned*)(ws + 196864);
    unsigned*       candI    = (unsigned*)(ws + 1245440);
    unsigned short* Wbf      = (unsigned short*)(ws + 2883584); // 256KB
    float*          B0       = (float*)(ws + 4194304);   // x_up f32
    float*          B1       = (float*)(ws + 37748736);  // ping / xT bf16
    unsigned short* xT       = (unsigned short*)(ws + 37748736);
    unsigned short* salbf    = (unsigned short*)(ws + 71303168); // 134MB
    float*          y        = (float*)(ws + 71303168);  // reuses salbf region

    hipMemsetAsync(d_ws, 0, 33024, stream);
    hipMemsetAsync(ws + 65792, 0, 131072, stream);

    cvtW_k<<<64,256,0,stream>>>(sal_w, Wbf);

    // ---- ConvUpsample: 128 -> 8192 frames (UPS decomposed, TT1) ----
    int Lc = 128;
    const float* src = x;
    for (int i = 0; i < 6; i++) {
        int Lo = Lc * 2;
        float* dst = (i % 2 == 0) ? B0 : B1;
        float inv_n = 1.f / (float)(NB * Lc);
        dim3 g(Lc / 64, 4, NB);
        if (i == 0)
            conv2_k<3,1,1,true,0,false,true,1,false><<<g,256,0,stream>>>(
                src, dst, up_w, up_b, nullptr, nullptr, nullptr, 0.f,
                stats, nullptr, Lc, Lo);
        else
            conv2_k<3,1,1,true,2,false,true,1,false><<<g,256,0,stream>>>(
                src, dst, up_w + i*NC*NC*3, up_b + i*NC,
                stats + (i-1)*256, up_g + (i-1)*NC, up_beta + (i-1)*NC, inv_n,
                stats + i*256, nullptr, Lc, Lo);
        src = dst; Lc = Lo;
    }
    // final k3 conv: B1 -> B0 (f32 x_up) + xT (bf16 transposed)
    conv2_k<3,1,1,false,2,false,false,2,true><<<dim3(LFULL/128, 4, NB),256,0,stream>>>(
        src, B0, up_out_w, up_out_b,
        stats + 5*256, up_g + 5*NC, up_beta + 5*NC, 1.f/(float)(NB*LFULL),
        nullptr, xT, LFULL, LFULL);

    // ---- SparseBottleneck ----
    salM_k<<<dim3(64,8,NB),256,0,stream>>>(xT, Wbf, sal_b, gsum, salbf, ghist);
    scan2_k<<<NB,256,0,stream>>>(ghist, thrv);
    filter_k<<<dim3(512,NB),256,0,stream>>>(salbf, thrv, candcnt, candI);
    recompute_k<<<dim3(1024,NB),128,0,stream>>>(candcnt, candI, B0, sal_w, sal_b, candK);
    select2_k<<<NB,256,0,stream>>>(candcnt, candK, candI, selected, selcnt);
    inity_k<<<(NB*NC*LFULL/4)/256,256,0,stream>>>(y, sb_dn_b);
    scatter_k<<<dim3(KSEL,NB),128,0,stream>>>(selected, selcnt, gsum, B0,
                                              sb_up_w, sb_up_b, sb_dn_w, y);

    // ---- down stack: 8192 -> 128 ----
    conv2_k<7,4,3,false,0,true,true,1,false><<<dim3(2048/64, 4, NB),256,0,stream>>>(
        y, B1, dn_w, dn_b, nullptr, nullptr, nullptr, 0.f,
        stats + 6*256, nullptr, 8192, 2048);
    conv2_k<7,4,3,false,1,true,true,1,false><<<dim3(512/64, 4, NB),256,0,stream>>>(
        B1, B0, dn_w + NC*NC*7, dn_b + NC,
        stats + 6*256, dn_g, dn_beta, 1.f/(float)(NB*2048),
        stats + 7*256, nullptr, 2048, 512);
    conv2_k<7,4,3,false,1,true,true,1,false><<<dim3(128/64, 4, NB),256,0,stream>>>(
        B0, B1, dn_w + 2*NC*NC*7, dn_b + 2*NC,
        stats + 7*256, dn_g + NC, dn_beta + NC, 1.f/(float)(NB*512),
        stats + 8*256, nullptr, 512, 128);

    apply_k<<<(out_size + 255)/256,256,0,stream>>>(
        B1, stats + 8*256, dn_g + 2*NC, dn_beta + 2*NC, (float*)d_out,
        1.f/(float)(NB*128));
}

// Round 6
// 1279.713 us; speedup vs baseline: 1.7380x; 1.0191x over previous
//
#include <hip/hip_runtime.h>
#include <hip/hip_bf16.h>

// ---------------------------------------------------------------------------
// ExpandAndContractBottleneck.  R6: convs use scalar-register weights (SMEM
// pipe) + async reg-staged x (LDS holds x only); sal pass split into two MFMA
// passes (hist, then direct candidate compaction) -- no 134MB sal buffer.
// ---------------------------------------------------------------------------

#define DEV_INLINE __device__ __forceinline__

constexpr int NB   = 8;
constexpr int NC   = 128;
constexpr int NH   = 1024;
constexpr int LFULL= 8192;
constexpr int KSEL = 512;
constexpr int CAP  = 32768;

typedef __attribute__((ext_vector_type(4))) float f32x4;
typedef __attribute__((ext_vector_type(8))) short bf16x8;

DEV_INLINE unsigned monoKey(float f) {
    unsigned u = __float_as_uint(f);
    return (u & 0x80000000u) ? ~u : (u | 0x80000000u);
}
DEV_INLINE float keyToF(unsigned k) {
    unsigned u = (k & 0x80000000u) ? (k ^ 0x80000000u) : ~k;
    return __uint_as_float(u);
}
DEV_INLINE unsigned monoKey16(unsigned u) {
    return (u & 0x8000u) ? ((~u) & 0xFFFFu) : (u | 0x8000u);
}
DEV_INLINE unsigned bf16r(float f) {
    unsigned u = __float_as_uint(f);
    return (u + 0x7FFFu + ((u >> 16) & 1u)) >> 16;
}
DEV_INLINE float lrelu(float v) { return v >= 0.f ? v : 0.2f * v; }

DEV_INLINE void loadg4(const float* __restrict__ rowp, int g0, int L, float* e) {
    if (g0 >= 0 && g0 + 4 <= L) {
        float4 v = *(const float4*)(rowp + g0);
        e[0] = v.x; e[1] = v.y; e[2] = v.z; e[3] = v.w;
    } else {
#pragma unroll
        for (int t = 0; t < 4; t++) {
            int g = g0 + t;
            e[t] = (g >= 0 && g < L) ? rowp[g] : 0.f;
        }
    }
}

// ---------------------------------------------------------------------------
// Weight prep: lay out all conv weights as [c][tap][128 oc] (UPS taps are the
// four 2x-decimation combos).  One thread per output element.
//   up layers:   off = layer*65536            (128c x 4r x 128o)
//   final conv:  off = 393216                 (128c x 3k x 128o)
//   down layers: off = 442368 + i*114688      (128c x 7k x 128o)
// ---------------------------------------------------------------------------
__global__ __launch_bounds__(256) void prep_k(
    const float* __restrict__ up_w, const float* __restrict__ up_out_w,
    const float* __restrict__ dn_w, float* __restrict__ wprep)
{
    int idx = blockIdx.x * 256 + threadIdx.x;          // 786432 total
    if (idx < 393216) {
        int layer = idx >> 16;
        int r0 = idx & 65535;
        int c = r0 >> 9, r = (r0 >> 7) & 3, o = r0 & 127;
        const float* wsrc = up_w + ((size_t)layer * 128 + o) * 384 + c * 3;
        float w0 = wsrc[0], w1 = wsrc[1], w2 = wsrc[2];
        wprep[idx] = (r == 0) ? w0 : (r == 1) ? (w1 + w2) : (r == 2) ? (w0 + w1) : w2;
    } else if (idx < 442368) {
        int r0 = idx - 393216;
        int c = r0 / 384, k = (r0 / 128) % 3, o = r0 & 127;
        wprep[idx] = up_out_w[((size_t)o * 128 + c) * 3 + k];
    } else {
        int r0 = idx - 442368;
        int layer = r0 / 114688;
        int r1 = r0 - layer * 114688;
        int c = r1 / 896, k = (r1 / 128) % 7, o = r1 & 127;
        wprep[idx] = dn_w[((size_t)layer * 128 + o) * 896 + c * 7 + k];
    }
}

// ---------------------------------------------------------------------------
// conv3: 256 thr = 4 waves; wave owns 8 wave-uniform oc (scalar weights);
// block = 32 oc (blockIdx.y) x PT t-positions.  LDS holds x only.
// Async staging: prefetch next c-chunk to regs during compute, write after.
// ---------------------------------------------------------------------------
template<int KW, int STRIDE, int PAD, bool UPS, int INMODE, bool OUTACT, bool STATS, int TT, bool XPOSE>
__global__ __launch_bounds__(256) void conv3_k(
    const float* __restrict__ in, float* __restrict__ out,
    const float* __restrict__ wp, const float* __restrict__ bias,
    const float* __restrict__ stp, const float* __restrict__ gp,
    const float* __restrict__ btp, float inv_n,
    float* __restrict__ stats, unsigned short* __restrict__ xtout,
    int L_in, int L_out)
{
    constexpr int CC    = (KW == 7) ? 8 : 16;
    constexpr int PT    = 64 * TT;                   // t-positions per block
    constexpr int TTO   = UPS ? 2 * TT : TT;         // outputs per thread
    constexpr int NWR   = UPS ? 4 : KW;
    constexpr int SPAN  = UPS ? (PT + 2) : ((PT - 1) * STRIDE + KW);
    constexpr int NCH   = (SPAN + 3) / 4;
    constexpr int XROW  = 4 * NCH + 4;
    constexpr int NLD   = (CC * NCH + 255) / 256;
    constexpr int XSPAN = UPS ? (TT + 2) : ((TT - 1) * STRIDE + KW);
    constexpr int STEP  = UPS ? TT : TT * STRIDE;

    __shared__ float xs[CC][XROW];
    __shared__ float scs[NC], shs[NC];

    const int b = blockIdx.z, ocb = blockIdx.y, tid = threadIdx.x;
    const int t0 = blockIdx.x * PT, lane = tid & 63;
    const int wid_u = __builtin_amdgcn_readfirstlane(tid >> 6);
    const int oc0 = ocb * 32 + wid_u * 8;            // wave-uniform
    const int gb = UPS ? (t0 - 1) : (t0 * STRIDE - PAD);
    const float* __restrict__ wpc = wp + oc0;

    if (INMODE > 0) {
        for (int c = tid; c < NC; c += 256) {
            float m  = stp[c] * inv_n;
            float va = stp[NC + c] * inv_n - m * m;
            float sc = gp[c] * rsqrtf(va + 1e-5f);
            scs[c] = sc;
            shs[c] = btp[c] - m * sc;
        }
        __syncthreads();
    }

    float acc[8][TTO];
#pragma unroll
    for (int i = 0; i < 8; i++)
#pragma unroll
        for (int j = 0; j < TTO; j++) acc[i][j] = 0.f;

    float pre[NLD][4];
    // ---- load + write chunk 0 ----
#pragma unroll
    for (int u = 0; u < NLD; u++) {
        int idx = tid + u * 256;
        if (idx < CC * NCH) {
            int cl = idx / NCH, q = idx - cl * NCH;
            loadg4(in + ((size_t)b * NC + cl) * L_in, gb + 4 * q, L_in, pre[u]);
        }
    }
#pragma unroll
    for (int u = 0; u < NLD; u++) {
        int idx = tid + u * 256;
        if (idx < CC * NCH) {
            int cl = idx / NCH, q = idx - cl * NCH;
            int g0 = gb + 4 * q;
            float e[4];
#pragma unroll
            for (int t = 0; t < 4; t++) {
                float v = pre[u][t];
                if (INMODE > 0) {
                    int g = g0 + t;
                    if (g >= 0 && g < L_in) {
                        float s = v * scs[cl] + shs[cl];
                        v = (INMODE == 2) ? lrelu(s) : s;
                    }
                }
                e[t] = v;
            }
            *(float4*)&xs[cl][4 * q] = make_float4(e[0], e[1], e[2], e[3]);
        }
    }
    __syncthreads();

    for (int cc = 0; cc < NC; cc += CC) {
        // ---- prefetch next chunk into registers (issue early) ----
        if (cc + CC < NC) {
#pragma unroll
            for (int u = 0; u < NLD; u++) {
                int idx = tid + u * 256;
                if (idx < CC * NCH) {
                    int cl = idx / NCH, q = idx - cl * NCH;
                    loadg4(in + ((size_t)b * NC + cc + CC + cl) * L_in,
                           gb + 4 * q, L_in, pre[u]);
                }
            }
        }
        // ---- compute current chunk ----
        for (int ci = 0; ci < CC; ci++) {
            const float* wrow = wpc + (size_t)(cc + ci) * (NWR * 128);
            float q[XSPAN];
            const int qb = lane * STEP;
            if constexpr ((STEP & 3) == 0) {
#pragma unroll
                for (int u = 0; u < XSPAN / 4; u++) {
                    float4 v = *(const float4*)&xs[ci][qb + 4 * u];
                    q[4*u] = v.x; q[4*u+1] = v.y; q[4*u+2] = v.z; q[4*u+3] = v.w;
                }
                if constexpr ((XSPAN & 3) >= 2) {
                    float2 v = *(const float2*)&xs[ci][qb + (XSPAN & ~3)];
                    q[(XSPAN & ~3)] = v.x; q[(XSPAN & ~3) + 1] = v.y;
                }
                if constexpr (XSPAN & 1) q[XSPAN - 1] = xs[ci][qb + XSPAN - 1];
            } else {
#pragma unroll
                for (int u = 0; u < XSPAN / 2; u++) {
                    float2 v = *(const float2*)&xs[ci][qb + 2 * u];
                    q[2*u] = v.x; q[2*u+1] = v.y;
                }
                if constexpr (XSPAN & 1) q[XSPAN - 1] = xs[ci][qb + XSPAN - 1];
            }
            if constexpr (UPS) {
#pragma unroll
                for (int i = 0; i < 8; i++) {
                    float w0  = wrow[i];
                    float w12 = wrow[128 + i];
                    float w01 = wrow[256 + i];
                    float w2  = wrow[384 + i];
#pragma unroll
                    for (int j = 0; j < TT; j++) {
                        acc[i][2*j]   = fmaf(w0,  q[j],     acc[i][2*j]);
                        acc[i][2*j]   = fmaf(w12, q[j + 1], acc[i][2*j]);
                        acc[i][2*j+1] = fmaf(w01, q[j + 1], acc[i][2*j+1]);
                        acc[i][2*j+1] = fmaf(w2,  q[j + 2], acc[i][2*j+1]);
                    }
                }
            } else {
#pragma unroll
                for (int k = 0; k < KW; k++) {
#pragma unroll
                    for (int i = 0; i < 8; i++) {
                        float w = wrow[k * 128 + i];
#pragma unroll
                        for (int j = 0; j < TT; j++)
                            acc[i][j] = fmaf(w, q[j * STRIDE + k], acc[i][j]);
                    }
                }
            }
        }
        __syncthreads();
        // ---- write prefetched chunk to LDS ----
        if (cc + CC < NC) {
#pragma unroll
            for (int u = 0; u < NLD; u++) {
                int idx = tid + u * 256;
                if (idx < CC * NCH) {
                    int cl = idx / NCH, q = idx - cl * NCH;
                    int g0 = gb + 4 * q;
                    int c = cc + CC + cl;
                    float e[4];
#pragma unroll
                    for (int t = 0; t < 4; t++) {
                        float v = pre[u][t];
                        if (INMODE > 0) {
                            int g = g0 + t;
                            if (g >= 0 && g < L_in) {
                                float s = v * scs[c] + shs[c];
                                v = (INMODE == 2) ? lrelu(s) : s;
                            }
                        }
                        e[t] = v;
                    }
                    *(float4*)&xs[cl][4 * q] = make_float4(e[0], e[1], e[2], e[3]);
                }
            }
            __syncthreads();
        }
    }

    // ---- epilogue ----
    const int po = (UPS ? 2 * t0 : t0) + lane * TTO;
    float tmpm[8][TTO];
#pragma unroll
    for (int i = 0; i < 8; i++) {
        const int o = oc0 + i;
        const float bv = bias[o];
        float s1 = 0.f, s2 = 0.f;
#pragma unroll
        for (int j = 0; j < TTO; j++) {
            float v = acc[i][j] + bv;
            if (OUTACT) v = lrelu(v);
            tmpm[i][j] = v;
            if (STATS) { s1 += v; s2 += v * v; }
        }
        float* orow = out + ((size_t)b * NC + o) * L_out + po;
        if constexpr (TTO == 4)
            *(float4*)orow = make_float4(tmpm[i][0], tmpm[i][1], tmpm[i][2], tmpm[i][3]);
        else if constexpr (TTO == 2)
            *(float2*)orow = make_float2(tmpm[i][0], tmpm[i][1]);
        else
            orow[0] = tmpm[i][0];
        if (STATS) {
#pragma unroll
            for (int m = 1; m < 64; m <<= 1) {
                s1 += __shfl_xor(s1, m);
                s2 += __shfl_xor(s2, m);
            }
            if (lane == 0) {
                atomicAdd(&stats[o], s1);
                atomicAdd(&stats[NC + o], s2);
            }
        }
    }
    if constexpr (XPOSE) {
#pragma unroll
        for (int j = 0; j < TTO; j++) {
            unsigned pk[4];
#pragma unroll
            for (int q4 = 0; q4 < 4; q4++)
                pk[q4] = bf16r(tmpm[2*q4][j]) | (bf16r(tmpm[2*q4+1][j]) << 16);
            *(uint4*)&xtout[((size_t)b * LFULL + po + j) * NC + oc0] =
                make_uint4(pk[0], pk[1], pk[2], pk[3]);
        }
    }
}

// ---------------------------------------------------------------------------
// cvtW: sal_w f32 [NH][NC] -> bf16
// ---------------------------------------------------------------------------
__global__ __launch_bounds__(256) void cvtW_k(const float* __restrict__ W,
                                              unsigned short* __restrict__ Wbf)
{
    int i = blockIdx.x * 256 + threadIdx.x;
    const float4 a = *(const float4*)&W[i * 8];
    const float4 b = *(const float4*)&W[i * 8 + 4];
    unsigned pk[4];
    pk[0] = bf16r(a.x) | (bf16r(a.y) << 16);
    pk[1] = bf16r(a.z) | (bf16r(a.w) << 16);
    pk[2] = bf16r(b.x) | (bf16r(b.y) << 16);
    pk[3] = bf16r(b.z) | (bf16r(b.w) << 16);
    *(uint4*)&Wbf[i * 8] = make_uint4(pk[0], pk[1], pk[2], pk[3]);
}

// ---------------------------------------------------------------------------
// salM2: MFMA bf16 GEMM over (128h x 128l) tiles.
//  PHASE 0: bf16-key histogram (4096 bins) + per-batch sum(exp)
//  PHASE 1: threshold -> ballot-compacted candidate indices
// ---------------------------------------------------------------------------
template<int PHASE>
__global__ __launch_bounds__(256) void salM2_k(
    const unsigned short* __restrict__ xT,   // [B][L][C] bf16
    const unsigned short* __restrict__ Wbf,  // [H][C] bf16
    const float* __restrict__ bias, float* __restrict__ gsum,
    unsigned* __restrict__ ghist, const unsigned* __restrict__ thrv,
    unsigned* __restrict__ candcnt, unsigned* __restrict__ candI)
{
    __shared__ unsigned short Als[128 * 128];  // swizzled [h][c]; P0: hist
    __shared__ unsigned short Bls[128 * 128];  // swizzled [l][c]; P0: red

    const int b  = blockIdx.z;
    const int h0 = blockIdx.y * 128;
    const int l0 = blockIdx.x * 128;
    const int tid = threadIdx.x;
    const int lane = tid & 63;
    const int wid = tid >> 6;
    const int wh = (wid >> 1) * 64;
    const int wl = (wid & 1) * 64;

    {
        const uint4* gA = (const uint4*)(Wbf + (size_t)h0 * NC);
        const uint4* gB = (const uint4*)(xT + ((size_t)b * LFULL + l0) * NC);
        char* cA = (char*)Als; char* cB = (char*)Bls;
        for (int i = tid; i < 2048; i += 256) {
            int row = i >> 4, q = i & 15;
            unsigned sw = (unsigned)(row * 256 + q * 16) ^ (((unsigned)(row & 7)) << 4);
            *(uint4*)(cA + sw) = gA[i];
        }
        for (int i = tid; i < 2048; i += 256) {
            int row = i >> 4, q = i & 15;
            unsigned sw = (unsigned)(row * 256 + q * 16) ^ (((unsigned)(row & 7)) << 4);
            *(uint4*)(cB + sw) = gB[i];
        }
    }
    __syncthreads();

    f32x4 acc[4][4];
#pragma unroll
    for (int i = 0; i < 4; i++)
#pragma unroll
        for (int j = 0; j < 4; j++) acc[i][j] = (f32x4)(0.f);

    const int r15 = lane & 15, g = lane >> 4;
#pragma unroll
    for (int ks = 0; ks < 4; ks++) {
        bf16x8 af[4], bfv[4];
#pragma unroll
        for (int f = 0; f < 4; f++) {
            int rowA = wh + f * 16 + r15;
            unsigned offA = (unsigned)(rowA * 256 + ks * 64 + g * 16)
                          ^ (((unsigned)(rowA & 7)) << 4);
            af[f] = *(const bf16x8*)((const char*)Als + offA);
            int rowB = wl + f * 16 + r15;
            unsigned offB = (unsigned)(rowB * 256 + ks * 64 + g * 16)
                          ^ (((unsigned)(rowB & 7)) << 4);
            bfv[f] = *(const bf16x8*)((const char*)Bls + offB);
        }
#pragma unroll
        for (int i = 0; i < 4; i++)
#pragma unroll
            for (int j = 0; j < 4; j++)
                acc[i][j] = __builtin_amdgcn_mfma_f32_16x16x32_bf16(
                    af[i], bfv[j], acc[i][j], 0, 0, 0);
    }

    if constexpr (PHASE == 0) {
        __syncthreads();                       // fragment reads done
        unsigned* lhist = (unsigned*)Als;      // 2 x 4096 replicas
        for (int i = tid; i < 8192; i += 256) lhist[i] = 0;
        __syncthreads();
        unsigned* myh = lhist + (tid & 1) * 4096;
        float expsum = 0.f;
#pragma unroll
        for (int i = 0; i < 4; i++) {
#pragma unroll
            for (int r = 0; r < 4; r++) {
                const int h = h0 + wh + i * 16 + g * 4 + r;
                const float bv = bias[h];
#pragma unroll
                for (int j = 0; j < 4; j++) {
                    float v = acc[i][j][r] + bv;
                    expsum += expf(v);
                    atomicAdd(&myh[monoKey16(bf16r(v)) >> 4], 1u);
                }
            }
        }
#pragma unroll
        for (int m = 1; m < 64; m <<= 1) expsum += __shfl_xor(expsum, m);
        float* red = (float*)Bls;
        if (lane == 0) red[wid] = expsum;
        __syncthreads();
        for (int i = tid; i < 4096; i += 256) {
            unsigned s = lhist[i] + lhist[4096 + i];
            if (s) atomicAdd(&ghist[b * 4096 + i], s);
        }
        if (tid == 0) atomicAdd(&gsum[b], red[0] + red[1] + red[2] + red[3]);
    } else {
        const unsigned thr = thrv[b * 2];
#pragma unroll
        for (int i = 0; i < 4; i++) {
#pragma unroll
            for (int r = 0; r < 4; r++) {
                const int h = h0 + wh + i * 16 + g * 4 + r;
                const float bv = bias[h];
#pragma unroll
                for (int j = 0; j < 4; j++) {
                    float v = acc[i][j][r] + bv;
                    bool pr = monoKey16(bf16r(v)) >= thr;
                    unsigned long long m = __ballot(pr);
                    if (m) {
                        int leader = __ffsll((unsigned long long)m) - 1;
                        int cnt = __popcll(m);
                        unsigned basepos = 0;
                        if (lane == leader)
                            basepos = atomicAdd(&candcnt[b], (unsigned)cnt);
                        basepos = __shfl(basepos, leader);
                        if (pr) {
                            int rr = __popcll(m & ((1ull << lane) - 1ull));
                            unsigned pos = basepos + (unsigned)rr;
                            if (pos < CAP) {
                                int l = l0 + wl + j * 16 + r15;
                                candI[b * CAP + pos] = (unsigned)((h << 13) | l);
                            }
                        }
                    }
                }
            }
        }
    }
}

// ---------------------------------------------------------------------------
__global__ __launch_bounds__(256) void scan2_k(
    const unsigned* __restrict__ ghist, unsigned* __restrict__ thrv)
{
    const int b = blockIdx.x, tid = threadIdx.x;
    __shared__ unsigned part[256];
    unsigned s = 0;
#pragma unroll
    for (int i = 0; i < 16; i++) s += ghist[b * 4096 + tid * 16 + i];
    part[tid] = s;
    __syncthreads();
    if (tid == 0) {
        unsigned cum = 0; int ch;
        for (ch = 255; ch >= 0; ch--) {
            if (cum + part[ch] >= KSEL) break;
            cum += part[ch];
        }
        int bin = 0;
        if (ch >= 0) {
            for (bin = ch * 16 + 15; bin > ch * 16; bin--) {
                unsigned c = ghist[b * 4096 + bin];
                if (cum + c >= KSEL) break;
                cum += c;
            }
        }
        int bcol = bin > 0 ? bin - 1 : 0;
        thrv[b * 2] = (unsigned)bcol << 4;
    }
}

__global__ __launch_bounds__(128) void recompute_k(
    const unsigned* __restrict__ candcnt, const unsigned* __restrict__ candI,
    const float* __restrict__ xu, const float* __restrict__ W,
    const float* __restrict__ bias, unsigned* __restrict__ candK)
{
    const int b = blockIdx.y;
    const unsigned cnt = min(candcnt[b], (unsigned)CAP);
    const int t = threadIdx.x;
    __shared__ float wsum[2];
    for (unsigned k = blockIdx.x; k < cnt; k += 1024) {
        unsigned e = candI[b * CAP + k];
        int h = e >> 13, l = e & 8191;
        float prod = W[h * NC + t] * xu[(b * NC + t) * LFULL + l];
#pragma unroll
        for (int m = 1; m < 64; m <<= 1) prod += __shfl_xor(prod, m);
        if ((t & 63) == 0) wsum[t >> 6] = prod;
        __syncthreads();
        if (t == 0) candK[b * CAP + k] = monoKey(wsum[0] + wsum[1] + bias[h]);
        __syncthreads();
    }
}

__global__ __launch_bounds__(256) void select2_k(
    const unsigned* __restrict__ candcnt, const unsigned* __restrict__ candK,
    const unsigned* __restrict__ candI,
    uint2* __restrict__ selected, unsigned* __restrict__ selcnt)
{
    const int b = blockIdx.x, tid = threadIdx.x;
    __shared__ unsigned h1[4096];
    __shared__ unsigned l2k[2048], l2i[2048];
    __shared__ unsigned part[256];
    __shared__ unsigned sh[8];

    const unsigned Nc = min(candcnt[b], (unsigned)CAP);
    const unsigned* kk = candK + b * CAP;
    const unsigned* ii = candI + b * CAP;
    uint2* sel = selected + b * KSEL;

    for (int i = tid; i < 4096; i += 256) h1[i] = 0;
    if (tid < 8) sh[tid] = 0;
    __syncthreads();
    for (unsigned i = tid; i < Nc; i += 256) atomicAdd(&h1[kk[i] >> 20], 1u);
    __syncthreads();
    {
        unsigned s = 0;
#pragma unroll
        for (int i = 0; i < 16; i++) s += h1[tid * 16 + i];
        part[tid] = s;
        __syncthreads();
        if (tid == 0) {
            unsigned cum = 0; int ch;
            for (ch = 255; ch >= 0; ch--) { if (cum + part[ch] >= KSEL) break; cum += part[ch]; }
            int bin = 0;
            if (ch >= 0)
                for (bin = ch * 16 + 15; bin > ch * 16; bin--) {
                    unsigned c = h1[bin];
                    if (cum + c >= KSEL) break;
                    cum += c;
                }
            sh[2] = (unsigned)bin; sh[3] = KSEL - cum;
        }
    }
    __syncthreads();
    const unsigned b1 = sh[2], need1 = sh[3];
    for (int i = tid; i < 1024; i += 256) h1[i] = 0;
    __syncthreads();
    for (unsigned i = tid; i < Nc; i += 256) {
        unsigned k = kk[i], bin = k >> 20;
        if (bin > b1) {
            unsigned p = atomicAdd(&sh[0], 1u);
            if (p < KSEL) sel[p] = make_uint2(k, ii[i]);
        } else if (bin == b1) {
            atomicAdd(&h1[(k >> 10) & 1023], 1u);
        }
    }
    __syncthreads();
    {
        unsigned s = 0;
#pragma unroll
        for (int i = 0; i < 4; i++) s += h1[tid * 4 + i];
        part[tid] = s;
        __syncthreads();
        if (tid == 0) {
            unsigned cum = 0; int ch;
            for (ch = 255; ch >= 0; ch--) { if (cum + part[ch] >= need1) break; cum += part[ch]; }
            int bin = 0;
            if (ch >= 0)
                for (bin = ch * 4 + 3; bin > ch * 4; bin--) {
                    unsigned c = h1[bin];
                    if (cum + c >= need1) break;
                    cum += c;
                }
            sh[4] = (unsigned)bin; sh[5] = need1 - cum;
        }
    }
    __syncthreads();
    const unsigned b2 = sh[4], need2 = sh[5];
    for (int i = tid; i < 1024; i += 256) h1[i] = 0;
    __syncthreads();
    for (unsigned i = tid; i < Nc; i += 256) {
        unsigned k = kk[i];
        if ((k >> 20) != b1) continue;
        unsigned mb = (k >> 10) & 1023;
        if (mb > b2) {
            unsigned p = atomicAdd(&sh[0], 1u);
            if (p < KSEL) sel[p] = make_uint2(k, ii[i]);
        } else if (mb == b2) {
            unsigned j = atomicAdd(&sh[1], 1u);
            if (j < 2048) { l2k[j] = k; l2i[j] = ii[i]; atomicAdd(&h1[k & 1023], 1u); }
        }
    }
    __syncthreads();
    const unsigned m2 = min(sh[1], 2048u);
    {
        unsigned s = 0;
#pragma unroll
        for (int i = 0; i < 4; i++) s += h1[tid * 4 + i];
        part[tid] = s;
        __syncthreads();
        if (tid == 0) {
            unsigned cum = 0; int ch;
            for (ch = 255; ch >= 0; ch--) { if (cum + part[ch] >= need2) break; cum += part[ch]; }
            int bin = 0;
            if (ch >= 0)
                for (bin = ch * 4 + 3; bin > ch * 4; bin--) {
                    unsigned c = h1[bin];
                    if (cum + c >= need2) break;
                    cum += c;
                }
            sh[6] = (unsigned)bin; sh[7] = need2 - cum;
        }
    }
    __syncthreads();
    const unsigned b3 = sh[6], need3 = sh[7];
    if (tid == 0) sh[1] = 0;
    __syncthreads();
    for (unsigned i = tid; i < m2; i += 256) {
        unsigned k = l2k[i], lb = k & 1023;
        if (lb > b3) {
            unsigned p = atomicAdd(&sh[0], 1u);
            if (p < KSEL) sel[p] = make_uint2(k, l2i[i]);
        } else if (lb == b3) {
            unsigned t = atomicAdd(&sh[1], 1u);
            if (t < need3) {
                unsigned p = atomicAdd(&sh[0], 1u);
                if (p < KSEL) sel[p] = make_uint2(k, l2i[i]);
            }
        }
    }
    __syncthreads();
    if (tid == 0) selcnt[b] = min(sh[0], (unsigned)KSEL);
}

// ---------------------------------------------------------------------------
__global__ void inity_k(float* __restrict__ y, const float* __restrict__ bias)
{
    int i = blockIdx.x * 256 + threadIdx.x;
    float bv = bias[(i >> 11) & 127];
    ((float4*)y)[i] = make_float4(bv, bv, bv, bv);
}

__global__ __launch_bounds__(128) void scatter_k(
    const uint2* __restrict__ selected, const unsigned* __restrict__ selcnt,
    const float* __restrict__ gsum, const float* __restrict__ xu,
    const float* __restrict__ upw, const float* __restrict__ upb,
    const float* __restrict__ dww, float* __restrict__ y)
{
    const int b = blockIdx.y, kidx = blockIdx.x;
    if (kidx >= (int)selcnt[b]) return;
    const uint2 s = selected[b * KSEL + kidx];
    const float salv = keyToF(s.x);
    const unsigned idx = s.y;
    const int h = idx >> 13, l = idx & 8191;
    const int t = threadIdx.x;

    float prod = upw[h * NC + t] * xu[(b * NC + t) * LFULL + l];
#pragma unroll
    for (int m = 1; m < 64; m <<= 1) prod += __shfl_xor(prod, m);
    __shared__ float wsum[2];
    if ((t & 63) == 0) wsum[t >> 6] = prod;
    __syncthreads();
    const float sig = wsum[0] + wsum[1] + upb[h];
    const float val = expf(salv) / gsum[b];
    const float g = sig * val;
    atomicAdd(&y[(b * NC + t) * LFULL + l], dww[t * NH + h] * g);
}

__global__ void apply_k(const float* __restrict__ in, const float* __restrict__ stats,
                        const float* __restrict__ g, const float* __restrict__ bt,
                        float* __restrict__ out, float inv_n)
{
    int i = blockIdx.x * 256 + threadIdx.x;
    int c = (i >> 7) & 127;
    float m  = stats[c] * inv_n;
    float va = stats[NC + c] * inv_n - m * m;
    float sc = g[c] * rsqrtf(va + 1e-5f);
    out[i] = in[i] * sc + (bt[c] - m * sc);
}

// ---------------------------------------------------------------------------
extern "C" void kernel_launch(void* const* d_in, const int* in_sizes, int n_in,
                              void* d_out, int out_size, void* d_ws, size_t ws_size,
                              hipStream_t stream)
{
    const float* x        = (const float*)d_in[0];
    const float* up_w     = (const float*)d_in[1];
    const float* up_b     = (const float*)d_in[2];
    const float* up_g     = (const float*)d_in[3];
    const float* up_beta  = (const float*)d_in[4];
    const float* up_out_w = (const float*)d_in[5];
    const float* up_out_b = (const float*)d_in[6];
    const float* sb_up_w  = (const float*)d_in[7];
    const float* sb_up_b  = (const float*)d_in[8];
    const float* sal_w    = (const float*)d_in[9];
    const float* sal_b    = (const float*)d_in[10];
    const float* sb_dn_w  = (const float*)d_in[11];
    const float* sb_dn_b  = (const float*)d_in[12];
    const float* dn_w     = (const float*)d_in[13];
    const float* dn_b     = (const float*)d_in[14];
    const float* dn_g     = (const float*)d_in[15];
    const float* dn_beta  = (const float*)d_in[16];

    char* ws = (char*)d_ws;
    float*          stats    = (float*)(ws + 0);          // 9x256 f32
    float*          gsum     = (float*)(ws + 16384);      // 8
    unsigned*       thrv     = (unsigned*)(ws + 16416);   // 8x2
    unsigned*       candcnt  = (unsigned*)(ws + 16480);   // 8
    unsigned*       selcnt   = (unsigned*)(ws + 16512);   // 8
    uint2*          selected = (uint2*)(ws + 16640);      // 8x512
    unsigned*       ghist    = (unsigned*)(ws + 49408);   // 8x4096
    unsigned*       candK    = (unsigned*)(ws + 180480);  // 8xCAP
    unsigned*       candI    = (unsigned*)(ws + 1229056); // 8xCAP
    unsigned short* Wbf      = (unsigned short*)(ws + 2277632); // 256KB
    float*          wprep    = (float*)(ws + 2539776);    // 3MB
    float*          B0       = (float*)(ws + 5685504);    // 33.5MB (x_up f32)
    float*          B1       = (float*)(ws + 39239936);   // 33.5MB ping
    unsigned short* xT       = (unsigned short*)(ws + 72794368); // bf16 16.7MB
    float*          y        = (float*)(ws + 72794368);   // f32 33.5MB (after xT)

    hipMemsetAsync(d_ws, 0, 16544, stream);
    hipMemsetAsync(ws + 49408, 0, 131072, stream);

    cvtW_k<<<64,256,0,stream>>>(sal_w, Wbf);
    prep_k<<<3072,256,0,stream>>>(up_w, up_out_w, dn_w, wprep);

    // ---- ConvUpsample: 128 -> 8192 frames (UPS decomposed, TT2) ----
    int Lc = 128;
    const float* src = x;
    for (int i = 0; i < 6; i++) {
        int Lo = Lc * 2;
        float* dst = (i % 2 == 0) ? B0 : B1;
        float inv_n = 1.f / (float)(NB * Lc);
        dim3 g(Lc / 128, 4, NB);
        if (i == 0)
            conv3_k<3,1,1,true,0,false,true,2,false><<<g,256,0,stream>>>(
                src, dst, wprep, up_b, nullptr, nullptr, nullptr, 0.f,
                stats, nullptr, Lc, Lo);
        else
            conv3_k<3,1,1,true,2,false,true,2,false><<<g,256,0,stream>>>(
                src, dst, wprep + i*65536, up_b + i*NC,
                stats + (i-1)*256, up_g + (i-1)*NC, up_beta + (i-1)*NC, inv_n,
                stats + i*256, nullptr, Lc, Lo);
        src = dst; Lc = Lo;
    }
    // final k3 conv: B1 -> B0 (f32 x_up) + xT (bf16 transposed)
    conv3_k<3,1,1,false,2,false,false,4,true><<<dim3(LFULL/256, 4, NB),256,0,stream>>>(
        src, B0, wprep + 393216, up_out_b,
        stats + 5*256, up_g + 5*NC, up_beta + 5*NC, 1.f/(float)(NB*LFULL),
        nullptr, xT, LFULL, LFULL);

    // ---- SparseBottleneck ----
    salM2_k<0><<<dim3(64,8,NB),256,0,stream>>>(xT, Wbf, sal_b, gsum, ghist,
                                               nullptr, nullptr, nullptr);
    scan2_k<<<NB,256,0,stream>>>(ghist, thrv);
    salM2_k<1><<<dim3(64,8,NB),256,0,stream>>>(xT, Wbf, sal_b, nullptr, nullptr,
                                               thrv, candcnt, candI);
    recompute_k<<<dim3(1024,NB),128,0,stream>>>(candcnt, candI, B0, sal_w, sal_b, candK);
    select2_k<<<NB,256,0,stream>>>(candcnt, candK, candI, selected, selcnt);
    inity_k<<<(NB*NC*LFULL/4)/256,256,0,stream>>>(y, sb_dn_b);
    scatter_k<<<dim3(KSEL,NB),128,0,stream>>>(selected, selcnt, gsum, B0,
                                              sb_up_w, sb_up_b, sb_dn_w, y);

    // ---- down stack: 8192 -> 128 ----
    conv3_k<7,4,3,false,0,true,true,2,false><<<dim3(2048/128, 4, NB),256,0,stream>>>(
        y, B1, wprep + 442368, dn_b, nullptr, nullptr, nullptr, 0.f,
        stats + 6*256, nullptr, 8192, 2048);
    conv3_k<7,4,3,false,1,true,true,2,false><<<dim3(512/128, 4, NB),256,0,stream>>>(
        B1, B0, wprep + 442368 + 114688, dn_b + NC,
        stats + 6*256, dn_g, dn_beta, 1.f/(float)(NB*2048),
        stats + 7*256, nullptr, 2048, 512);
    conv3_k<7,4,3,false,1,true,true,2,false><<<dim3(128/128, 4, NB),256,0,stream>>>(
        B0, B1, wprep + 442368 + 2*114688, dn_b + 2*NC,
        stats + 7*256, dn_g + NC, dn_beta + NC, 1.f/(float)(NB*512),
        stats + 8*256, nullptr, 512, 128);

    apply_k<<<(out_size + 255)/256,256,0,stream>>>(
        B1, stats + 8*256, dn_g + 2*NC, dn_beta + 2*NC, (float*)d_out,
        1.f/(float)(NB*128));
}